// Round 2
// baseline (1577.160 us; speedup 1.0000x reference)
//
#include <hip/hip_runtime.h>

#define NN 50000
#define NE 800000
#define NG 64
#define D 128
#define DP 256
#define BN_EPS 1e-5f

typedef unsigned short bf16;

__device__ __forceinline__ float bf2f(unsigned h16) {
  unsigned u = (h16 & 0xffffu) << 16; float f; __builtin_memcpy(&f, &u, 4); return f;
}
__device__ __forceinline__ bf16 f2bf(float f) {
  unsigned u; __builtin_memcpy(&u, &f, 4);
  return (bf16)((u + 0x7FFFu + ((u >> 16) & 1u)) >> 16);
}

// ---------- dtype detection: 1 = bf16, 0 = f32 ----------
__global__ void k_detect(const unsigned short* __restrict__ x, int* __restrict__ flag) {
  if (threadIdx.x == 0) {
    int good = 0;
    for (int i = 0; i < 64; ++i) {
      float v = bf2f(x[2 * i]);
      float a = fabsf(v);
      if (v == 0.0f || (a > 1e-30f && a < 32.0f)) good++;
    }
    flag[0] = (good >= 56) ? 1 : 0;
  }
}

// ---------- convert all weight tensors to f32 in ws ----------
struct CvtArgs {
  const void* s[12];
  float* d[12];
  int n[12];
};

__global__ __launch_bounds__(256) void k_cvt(CvtArgs a, const int* __restrict__ flag) {
  int t = blockIdx.x;
  int mode = flag[0];
  const void* sp = a.s[t];
  float* dp = a.d[t];
  int n = a.n[t];
  if (mode) {
    const unsigned short* s = (const unsigned short*)sp;
    for (int i = threadIdx.x; i < n; i += 256) dp[i] = bf2f(s[i]);
  } else {
    const float* s = (const float*)sp;
    for (int i = threadIdx.x; i < n; i += 256) dp[i] = s[i];
  }
}

// ---------- degree ----------
__global__ __launch_bounds__(256) void k_deg(const int* __restrict__ ei, int* __restrict__ cnt) {
  int e = blockIdx.x * 256 + threadIdx.x;
  if (e < NE) atomicAdd(&cnt[ei[NE + e]], 1);
}

__global__ __launch_bounds__(256) void k_invd(const int* __restrict__ cnt,
                                              float* __restrict__ inv_deg,
                                              float* __restrict__ isq) {
  int i = blockIdx.x * 256 + threadIdx.x;
  if (i < NN) {
    float dg = (float)(cnt[i] + 1);
    inv_deg[i] = 1.0f / dg;
    isq[i] = rsqrtf(dg);
  }
}

// ---------- GEMM: Out[n][j] = sum_k X[n][k]*(scale?s[k]:1)*W[k][j] + (rowadd?ra[j]:0) ----------
// X dtype selected at runtime via flag (null flag -> f32). In-place (Out==X) is safe:
// rows are staged to LDS before stores, and blocks own disjoint row tiles.
__global__ __launch_bounds__(256) void k_gemm(const void* Xv, const int* __restrict__ flag,
                                              const float* __restrict__ W,
                                              const float* __restrict__ scale,
                                              const float* __restrict__ rowadd,
                                              float* Out, int nrows) {
  __shared__ float Wl[D * D];      // 64 KB
  __shared__ float Xs[32][D];      // 16 KB
  int mode = flag ? flag[0] : 0;
  for (int i = threadIdx.x; i < D * D / 4; i += 256) {
    float4 w = ((const float4*)W)[i];
    float sc = scale ? scale[i >> 5] : 1.0f;   // 32 float4-chunks per row
    ((float4*)Wl)[i] = make_float4(w.x * sc, w.y * sc, w.z * sc, w.w * sc);
  }
  int jg = threadIdx.x & 31, rg = threadIdx.x >> 5;
  float4 rav = make_float4(0.f, 0.f, 0.f, 0.f);
  if (rowadd) rav = ((const float4*)rowadd)[jg];
  for (int tile = blockIdx.x * 32; tile < nrows; tile += gridDim.x * 32) {
    int rows = min(32, nrows - tile);
    __syncthreads();   // protect Wl (first iter) and Xs (later iters)
    if (mode) {
      const bf16* X = (const bf16*)Xv;
      for (int i = threadIdx.x; i < rows * (D / 8); i += 256) {
        int r = i >> 4, c8 = i & 15;
        uint4 raw = ((const uint4*)(X + (size_t)(tile + r) * D))[c8];
        float* xp = &Xs[r][c8 * 8];
        xp[0] = bf2f(raw.x & 0xffff); xp[1] = bf2f(raw.x >> 16);
        xp[2] = bf2f(raw.y & 0xffff); xp[3] = bf2f(raw.y >> 16);
        xp[4] = bf2f(raw.z & 0xffff); xp[5] = bf2f(raw.z >> 16);
        xp[6] = bf2f(raw.w & 0xffff); xp[7] = bf2f(raw.w >> 16);
      }
    } else {
      const float* X = (const float*)Xv;
      for (int i = threadIdx.x; i < rows * (D / 4); i += 256) {
        int r = i >> 5, c = i & 31;
        ((float4*)Xs[r])[c] = ((const float4*)(X + (size_t)(tile + r) * D))[c];
      }
    }
    __syncthreads();
    float4 a0 = rav, a1 = rav, a2 = rav, a3 = rav;
#pragma unroll 4
    for (int k = 0; k < D; ++k) {
      float4 wv = ((float4*)&Wl[k * D])[jg];
      float x0 = Xs[rg * 4 + 0][k], x1 = Xs[rg * 4 + 1][k];
      float x2 = Xs[rg * 4 + 2][k], x3 = Xs[rg * 4 + 3][k];
      a0.x += x0 * wv.x; a0.y += x0 * wv.y; a0.z += x0 * wv.z; a0.w += x0 * wv.w;
      a1.x += x1 * wv.x; a1.y += x1 * wv.y; a1.z += x1 * wv.z; a1.w += x1 * wv.w;
      a2.x += x2 * wv.x; a2.y += x2 * wv.y; a2.z += x2 * wv.z; a2.w += x2 * wv.w;
      a3.x += x3 * wv.x; a3.y += x3 * wv.y; a3.z += x3 * wv.z; a3.w += x3 * wv.w;
    }
    int r0 = tile + rg * 4;
    if (r0 + 0 < nrows) ((float4*)(Out + (size_t)(r0 + 0) * D))[jg] = a0;
    if (r0 + 1 < nrows) ((float4*)(Out + (size_t)(r0 + 1) * D))[jg] = a1;
    if (r0 + 2 < nrows) ((float4*)(Out + (size_t)(r0 + 2) * D))[jg] = a2;
    if (r0 + 3 < nrows) ((float4*)(Out + (size_t)(r0 + 3) * D))[jg] = a3;
  }
}

// ---------- edge scatter: agg[dst] += H[src] * isq[src]*isq[dst] ----------
__global__ __launch_bounds__(256) void k_scatter(const int* __restrict__ ei, const float* __restrict__ H,
                                                 const float* __restrict__ isq, float* __restrict__ agg) {
  int wid = threadIdx.x >> 6, lane = threadIdx.x & 63;
  int ebase = (blockIdx.x * 4 + wid) * 4;
#pragma unroll
  for (int i = 0; i < 4; ++i) {
    int e = ebase + i;
    if (e < NE) {
      int s = ei[e], d = ei[NE + e];
      float c = isq[s] * isq[d];
      float2 hv = ((const float2*)(H + (size_t)s * D))[lane];
      float* ap = agg + (size_t)d * D + lane * 2;
      atomicAdd(ap, hv.x * c);
      atomicAdd(ap + 1, hv.y * c);
    }
  }
}

// ---------- combine1: r = relu(agg + H*inv_deg + b); BN partial sums; Rout may alias H ----------
__global__ __launch_bounds__(256) void k_combine1(const float* __restrict__ agg, const float* H,
                                                  const float* __restrict__ inv_deg, const float* __restrict__ b,
                                                  float* Rout,
                                                  float* __restrict__ sum, float* __restrict__ sumsq) {
  int k = threadIdx.x & 127, half = threadIdx.x >> 7;
  __shared__ float ssum[256], ssq[256];
  float bk = b[k];
  float ls = 0.f, lq = 0.f;
  int base = blockIdx.x * 64, end = min(base + 64, NN);
  for (int n = base + half; n < end; n += 2) {
    size_t idx = (size_t)n * D + k;
    float r = fmaxf(agg[idx] + H[idx] * inv_deg[n] + bk, 0.f);
    Rout[idx] = r;
    ls += r; lq += r * r;
  }
  ssum[threadIdx.x] = ls; ssq[threadIdx.x] = lq;
  __syncthreads();
  if (half == 0) {
    atomicAdd(&sum[k], ssum[k] + ssum[k + 128]);
    atomicAdd(&sumsq[k], ssq[k] + ssq[k + 128]);
  }
}

// ---------- combine2: BN sums + per-graph max pool of relu values ----------
__global__ __launch_bounds__(256) void k_combine2(const float* __restrict__ agg, const float* __restrict__ H,
                                                  const float* __restrict__ inv_deg, const float* __restrict__ b,
                                                  const int* __restrict__ batch,
                                                  float* __restrict__ sum, float* __restrict__ sumsq,
                                                  float* __restrict__ pooled) {
  int k = threadIdx.x & 127, half = threadIdx.x >> 7;
  __shared__ float ssum[256], ssq[256];
  float bk = b[k];
  float ls = 0.f, lq = 0.f;
  int base = blockIdx.x * 64, end = min(base + 64, NN);
  int gcur = -1; float mx = 0.f;
  for (int n = base + half; n < end; n += 2) {
    size_t idx = (size_t)n * D + k;
    float r = fmaxf(agg[idx] + H[idx] * inv_deg[n] + bk, 0.f);
    ls += r; lq += r * r;
    int g = batch[n];
    if (g != gcur) {
      if (gcur >= 0) atomicMax((int*)&pooled[(size_t)gcur * D + k], __float_as_int(mx));
      gcur = g; mx = 0.f;
    }
    mx = fmaxf(mx, r);
  }
  if (gcur >= 0) atomicMax((int*)&pooled[(size_t)gcur * D + k], __float_as_int(mx));
  ssum[threadIdx.x] = ls; ssq[threadIdx.x] = lq;
  __syncthreads();
  if (half == 0) {
    atomicAdd(&sum[k], ssum[k] + ssum[k + 128]);
    atomicAdd(&sumsq[k], ssq[k] + ssq[k + 128]);
  }
}

// ---------- BN stats; layer1 also folds t1 @ W2 ----------
__global__ void k_bnstats1(const float* __restrict__ sum, const float* __restrict__ sumsq,
                           const float* __restrict__ gamma, const float* __restrict__ beta,
                           const float* __restrict__ W2,
                           float* __restrict__ svec, float* __restrict__ tW2) {
  __shared__ float t[D];
  int k = threadIdx.x;
  float mean = sum[k] * (1.0f / NN);
  float var = sumsq[k] * (1.0f / NN) - mean * mean;
  float s = gamma[k] * rsqrtf(var + BN_EPS);
  svec[k] = s;
  t[k] = beta[k] - mean * s;
  __syncthreads();
  float acc = 0.f;
  for (int kk = 0; kk < D; ++kk) acc += t[kk] * W2[kk * D + k];
  tW2[k] = acc;
}

__global__ void k_bnstats2(const float* __restrict__ sum, const float* __restrict__ sumsq,
                           const float* __restrict__ gamma, const float* __restrict__ beta,
                           float* __restrict__ svec, float* __restrict__ tvec) {
  int k = threadIdx.x;
  float mean = sum[k] * (1.0f / NN);
  float var = sumsq[k] * (1.0f / NN) - mean * mean;
  float s = gamma[k] * rsqrtf(var + BN_EPS);
  svec[k] = s;
  tvec[k] = beta[k] - mean * s;
}

// ---------- head MLP: per graph; output dtype follows detected mode ----------
__global__ __launch_bounds__(256) void k_head(const float* __restrict__ pooled, const float* __restrict__ s2,
                                              const float* __restrict__ t2, const float* __restrict__ Wp1,
                                              const float* __restrict__ bp1, const float* __restrict__ Wp2,
                                              const float* __restrict__ bp2, void* out,
                                              const int* __restrict__ flag) {
  __shared__ float y[D];
  __shared__ float wr[4];
  int g = blockIdx.x, j = threadIdx.x;
  if (j < D) y[j] = pooled[(size_t)g * D + j] * s2[j] + t2[j];
  __syncthreads();
  float acc = bp1[j];
#pragma unroll 4
  for (int k = 0; k < D; ++k) acc += y[k] * Wp1[k * DP + j];
  float v = fmaxf(acc, 0.f) * Wp2[j];
  for (int off = 32; off; off >>= 1) v += __shfl_down(v, off);
  if ((j & 63) == 0) wr[j >> 6] = v;
  __syncthreads();
  if (j == 0) {
    float r = wr[0] + wr[1] + wr[2] + wr[3] + bp2[0];
    if (flag[0]) ((bf16*)out)[g] = f2bf(r);
    else ((float*)out)[g] = r;
  }
}

extern "C" void kernel_launch(void* const* d_in, const int* in_sizes, int n_in,
                              void* d_out, int out_size, void* d_ws, size_t ws_size,
                              hipStream_t stream) {
  const void* x   = d_in[0];
  const int*  ei  = (const int*)d_in[1];
  const int*  bat = (const int*)d_in[2];

  float* f = (float*)d_ws;
  float* A = f; f += (size_t)NN * D;   // H1 -> R1 (in-place) -> H2 (in-place)
  float* B = f; f += (size_t)NN * D;   // AGG (zeroed per layer)
  float* W1f  = f; f += D * D;
  float* W2f  = f; f += D * D;
  float* Wp1f = f; f += D * DP;
  float* b1f  = f; f += D;
  float* g1f  = f; f += D;
  float* be1f = f; f += D;
  float* b2f  = f; f += D;
  float* g2f  = f; f += D;
  float* be2f = f; f += D;
  float* bp1f = f; f += DP;
  float* Wp2f = f; f += DP;
  float* bp2f = f; f += 4;
  float* sum1   = f; f += D;
  float* sumsq1 = f; f += D;
  float* sum2   = f; f += D;
  float* sumsq2 = f; f += D;
  float* pooled = f; f += (size_t)NG * D;
  float* svec1  = f; f += D;
  float* tW2    = f; f += D;
  float* svec2  = f; f += D;
  float* tvec2  = f; f += D;
  float* inv_deg = f; f += NN;
  float* isq     = f; f += NN;
  int* cnt  = (int*)f; f += NN;
  int* flag = (int*)f;

  hipMemsetAsync(cnt, 0, NN * sizeof(int), stream);
  hipMemsetAsync(B, 0, (size_t)NN * D * sizeof(float), stream);
  hipMemsetAsync(sum1, 0, (4 * D + NG * D) * sizeof(float), stream);

  k_detect<<<1, 64, 0, stream>>>((const unsigned short*)x, flag);

  CvtArgs ca;
  ca.s[0] = d_in[3];  ca.d[0] = W1f;  ca.n[0] = D * D;
  ca.s[1] = d_in[7];  ca.d[1] = W2f;  ca.n[1] = D * D;
  ca.s[2] = d_in[11]; ca.d[2] = Wp1f; ca.n[2] = D * DP;
  ca.s[3] = d_in[4];  ca.d[3] = b1f;  ca.n[3] = D;
  ca.s[4] = d_in[5];  ca.d[4] = g1f;  ca.n[4] = D;
  ca.s[5] = d_in[6];  ca.d[5] = be1f; ca.n[5] = D;
  ca.s[6] = d_in[8];  ca.d[6] = b2f;  ca.n[6] = D;
  ca.s[7] = d_in[9];  ca.d[7] = g2f;  ca.n[7] = D;
  ca.s[8] = d_in[10]; ca.d[8] = be2f; ca.n[8] = D;
  ca.s[9] = d_in[12]; ca.d[9] = bp1f; ca.n[9] = DP;
  ca.s[10] = d_in[13]; ca.d[10] = Wp2f; ca.n[10] = DP;
  ca.s[11] = d_in[14]; ca.d[11] = bp2f; ca.n[11] = 1;
  k_cvt<<<12, 256, 0, stream>>>(ca, flag);

  k_deg<<<(NE + 255) / 256, 256, 0, stream>>>(ei, cnt);
  k_invd<<<(NN + 255) / 256, 256, 0, stream>>>(cnt, inv_deg, isq);

  k_gemm<<<(NN + 31) / 32, 256, 0, stream>>>(x, flag, W1f, nullptr, nullptr, A, NN);
  k_scatter<<<(NE + 15) / 16, 256, 0, stream>>>(ei, A, isq, B);
  k_combine1<<<(NN + 63) / 64, 256, 0, stream>>>(B, A, inv_deg, b1f, A, sum1, sumsq1);
  k_bnstats1<<<1, D, 0, stream>>>(sum1, sumsq1, g1f, be1f, W2f, svec1, tW2);

  hipMemsetAsync(B, 0, (size_t)NN * D * sizeof(float), stream);
  k_gemm<<<(NN + 31) / 32, 256, 0, stream>>>(A, nullptr, W2f, svec1, tW2, A, NN);
  k_scatter<<<(NE + 15) / 16, 256, 0, stream>>>(ei, A, isq, B);
  k_combine2<<<(NN + 63) / 64, 256, 0, stream>>>(B, A, inv_deg, b2f, bat, sum2, sumsq2, pooled);
  k_bnstats2<<<1, D, 0, stream>>>(sum2, sumsq2, g2f, be2f, svec2, tvec2);

  k_head<<<NG, DP, 0, stream>>>(pooled, svec2, tvec2, Wp1f, bp1f, Wp2f, bp2f, d_out, flag);
}

// Round 3
// 539.304 us; speedup vs baseline: 2.9244x; 2.9244x over previous
//
#include <hip/hip_runtime.h>

#define NN 50000
#define NE 800000
#define NG 64
#define D 128
#define DP 256
#define BN_EPS 1e-5f
#define NSLOT 32

typedef unsigned short bf16;

__device__ __forceinline__ float bf2f(unsigned h16) {
  unsigned u = (h16 & 0xffffu) << 16; float f; __builtin_memcpy(&f, &u, 4); return f;
}
__device__ __forceinline__ bf16 f2bf(float f) {
  unsigned u; __builtin_memcpy(&u, &f, 4);
  return (bf16)((u + 0x7FFFu + ((u >> 16) & 1u)) >> 16);
}

// ---------- dtype detection: 1 = bf16, 0 = f32 ----------
__global__ void k_detect(const unsigned short* __restrict__ x, int* __restrict__ flag) {
  if (threadIdx.x == 0) {
    int good = 0;
    for (int i = 0; i < 64; ++i) {
      float v = bf2f(x[2 * i]);
      float a = fabsf(v);
      if (v == 0.0f || (a > 1e-30f && a < 32.0f)) good++;
    }
    flag[0] = (good >= 56) ? 1 : 0;
  }
}

// ---------- convert all weight tensors to f32 in ws ----------
struct CvtArgs {
  const void* s[12];
  float* d[12];
  int n[12];
};

__global__ __launch_bounds__(256) void k_cvt(CvtArgs a, const int* __restrict__ flag) {
  int t = blockIdx.x;
  int mode = flag[0];
  const void* sp = a.s[t];
  float* dp = a.d[t];
  int n = a.n[t];
  if (mode) {
    const unsigned short* s = (const unsigned short*)sp;
    for (int i = threadIdx.x; i < n; i += 256) dp[i] = bf2f(s[i]);
  } else {
    const float* s = (const float*)sp;
    for (int i = threadIdx.x; i < n; i += 256) dp[i] = s[i];
  }
}

// ---------- degree count ----------
__global__ __launch_bounds__(256) void k_deg(const int* __restrict__ ei, int* __restrict__ cnt) {
  int e = blockIdx.x * 256 + threadIdx.x;
  if (e < NE) atomicAdd(&cnt[ei[NE + e]], 1);
}

// ---------- isq[i] = 1/sqrt(deg_i), deg_i = cnt+1 ----------
__global__ __launch_bounds__(256) void k_invd(const int* __restrict__ cnt, float* __restrict__ isq) {
  int i = blockIdx.x * 256 + threadIdx.x;
  if (i < NN) isq[i] = rsqrtf((float)(cnt[i] + 1));
}

// ---------- exclusive prefix scan over cnt -> rowoff[NN+1], cursor copy ----------
__global__ __launch_bounds__(1024) void k_scan(const int* __restrict__ cnt,
                                               int* __restrict__ ro, int* __restrict__ cursor) {
  __shared__ int part[1024];
  const int CH = (NN + 1023) / 1024;  // 49
  int t = threadIdx.x;
  int lo = t * CH, hi = min(lo + CH, NN);
  int s = 0;
  for (int i = lo; i < hi; ++i) s += cnt[i];
  part[t] = s;
  __syncthreads();
  for (int off = 1; off < 1024; off <<= 1) {
    int v = (t >= off) ? part[t - off] : 0;
    __syncthreads();
    part[t] += v;
    __syncthreads();
  }
  int run = part[t] - s;  // exclusive base
  for (int i = lo; i < hi; ++i) {
    ro[i] = run; cursor[i] = run;
    run += cnt[i];
  }
  if (t == 1023) ro[NN] = run;
}

// ---------- fill CSR: csr_src[slot], csr_c[slot] = isq[s]*isq[d] ----------
__global__ __launch_bounds__(256) void k_fill(const int* __restrict__ ei, const float* __restrict__ isq,
                                              int* __restrict__ cursor,
                                              int* __restrict__ csr_src, float* __restrict__ csr_c) {
  int e = blockIdx.x * 256 + threadIdx.x;
  if (e < NE) {
    int s = ei[e], d = ei[NE + e];
    int slot = atomicAdd(&cursor[d], 1);
    csr_src[slot] = s;
    csr_c[slot] = isq[s] * isq[d];
  }
}

// ---------- GEMM: Out[n][j] = sum_k X[n][k]*(scale?s[k]:1)*W[k][j] + (rowadd?ra[j]:0) ----------
__global__ __launch_bounds__(256) void k_gemm(const void* Xv, const int* __restrict__ flag,
                                              const float* __restrict__ W,
                                              const float* __restrict__ scale,
                                              const float* __restrict__ rowadd,
                                              float* Out, int nrows) {
  __shared__ float Wl[D * D];      // 64 KB
  __shared__ float Xs[32][D];      // 16 KB
  int mode = flag ? flag[0] : 0;
  for (int i = threadIdx.x; i < D * D / 4; i += 256) {
    float4 w = ((const float4*)W)[i];
    float sc = scale ? scale[i >> 5] : 1.0f;
    ((float4*)Wl)[i] = make_float4(w.x * sc, w.y * sc, w.z * sc, w.w * sc);
  }
  int jg = threadIdx.x & 31, rg = threadIdx.x >> 5;
  float4 rav = make_float4(0.f, 0.f, 0.f, 0.f);
  if (rowadd) rav = ((const float4*)rowadd)[jg];
  for (int tile = blockIdx.x * 32; tile < nrows; tile += gridDim.x * 32) {
    int rows = min(32, nrows - tile);
    __syncthreads();
    if (mode) {
      const bf16* X = (const bf16*)Xv;
      for (int i = threadIdx.x; i < rows * (D / 8); i += 256) {
        int r = i >> 4, c8 = i & 15;
        uint4 raw = ((const uint4*)(X + (size_t)(tile + r) * D))[c8];
        float* xp = &Xs[r][c8 * 8];
        xp[0] = bf2f(raw.x & 0xffff); xp[1] = bf2f(raw.x >> 16);
        xp[2] = bf2f(raw.y & 0xffff); xp[3] = bf2f(raw.y >> 16);
        xp[4] = bf2f(raw.z & 0xffff); xp[5] = bf2f(raw.z >> 16);
        xp[6] = bf2f(raw.w & 0xffff); xp[7] = bf2f(raw.w >> 16);
      }
    } else {
      const float* X = (const float*)Xv;
      for (int i = threadIdx.x; i < rows * (D / 4); i += 256) {
        int r = i >> 5, c = i & 31;
        ((float4*)Xs[r])[c] = ((const float4*)(X + (size_t)(tile + r) * D))[c];
      }
    }
    __syncthreads();
    float4 a0 = rav, a1 = rav, a2 = rav, a3 = rav;
#pragma unroll 4
    for (int k = 0; k < D; ++k) {
      float4 wv = ((float4*)&Wl[k * D])[jg];
      float x0 = Xs[rg * 4 + 0][k], x1 = Xs[rg * 4 + 1][k];
      float x2 = Xs[rg * 4 + 2][k], x3 = Xs[rg * 4 + 3][k];
      a0.x += x0 * wv.x; a0.y += x0 * wv.y; a0.z += x0 * wv.z; a0.w += x0 * wv.w;
      a1.x += x1 * wv.x; a1.y += x1 * wv.y; a1.z += x1 * wv.z; a1.w += x1 * wv.w;
      a2.x += x2 * wv.x; a2.y += x2 * wv.y; a2.z += x2 * wv.z; a2.w += x2 * wv.w;
      a3.x += x3 * wv.x; a3.y += x3 * wv.y; a3.z += x3 * wv.z; a3.w += x3 * wv.w;
    }
    int r0 = tile + rg * 4;
    if (r0 + 0 < nrows) ((float4*)(Out + (size_t)(r0 + 0) * D))[jg] = a0;
    if (r0 + 1 < nrows) ((float4*)(Out + (size_t)(r0 + 1) * D))[jg] = a1;
    if (r0 + 2 < nrows) ((float4*)(Out + (size_t)(r0 + 2) * D))[jg] = a2;
    if (r0 + 3 < nrows) ((float4*)(Out + (size_t)(r0 + 3) * D))[jg] = a3;
  }
}

// ---------- CSR aggregation + fused epilogue ----------
// wave handles 4 nodes; lane owns columns (2*lane, 2*lane+1).
// r = relu(sum_{e in-edges} H[src_e]*c_e + H[n]/deg_n + b)
// LAYER2: also per-graph max pool (batch sorted). LAYER1: write r to Rout.
template <int LAYER2>
__global__ __launch_bounds__(256) void k_agg(const float* __restrict__ H, const int* __restrict__ ro,
                                             const int* __restrict__ csr_src, const float* __restrict__ csr_c,
                                             const float* __restrict__ b, const int* __restrict__ batch,
                                             float* __restrict__ Rout,
                                             float* __restrict__ sumP, float* __restrict__ sumsqP,
                                             float* __restrict__ pooled) {
  int lane = threadIdx.x & 63, w = threadIdx.x >> 6;
  int nbase = blockIdx.x * 16 + w * 4;
  float2 bv = ((const float2*)b)[lane];
  float2 ls = make_float2(0.f, 0.f), lq = make_float2(0.f, 0.f);
  int gcur = -1; float2 mx = make_float2(0.f, 0.f);
  int nend = min(nbase + 4, NN);
  for (int n = nbase; n < nend; ++n) {
    int r0 = ro[n], r1 = ro[n + 1];
    float invd = 1.0f / (float)(r1 - r0 + 1);
    float2 hv = ((const float2*)(H + (size_t)n * D))[lane];
    float2 acc = make_float2(hv.x * invd, hv.y * invd);
    for (int e = r0; e < r1; ++e) {
      int s = csr_src[e];
      float c = csr_c[e];
      float2 xv = ((const float2*)(H + (size_t)s * D))[lane];
      acc.x += xv.x * c; acc.y += xv.y * c;
    }
    float2 r = make_float2(fmaxf(acc.x + bv.x, 0.f), fmaxf(acc.y + bv.y, 0.f));
    if (!LAYER2) ((float2*)(Rout + (size_t)n * D))[lane] = r;
    ls.x += r.x; ls.y += r.y; lq.x += r.x * r.x; lq.y += r.y * r.y;
    if (LAYER2) {
      int g = batch[n];
      if (g != gcur) {
        if (gcur >= 0) {
          atomicMax((int*)&pooled[(size_t)gcur * D + 2 * lane], __float_as_int(mx.x));
          atomicMax((int*)&pooled[(size_t)gcur * D + 2 * lane + 1], __float_as_int(mx.y));
        }
        gcur = g; mx = make_float2(0.f, 0.f);
      }
      mx.x = fmaxf(mx.x, r.x); mx.y = fmaxf(mx.y, r.y);
    }
  }
  if (LAYER2 && gcur >= 0) {
    atomicMax((int*)&pooled[(size_t)gcur * D + 2 * lane], __float_as_int(mx.x));
    atomicMax((int*)&pooled[(size_t)gcur * D + 2 * lane + 1], __float_as_int(mx.y));
  }
  __shared__ float ss[4][D], sq[4][D];
  ss[w][2 * lane] = ls.x; ss[w][2 * lane + 1] = ls.y;
  sq[w][2 * lane] = lq.x; sq[w][2 * lane + 1] = lq.y;
  __syncthreads();
  int slot = (blockIdx.x & (NSLOT - 1)) * D;
  if (threadIdx.x < D) {
    int k = threadIdx.x;
    atomicAdd(&sumP[slot + k], ss[0][k] + ss[1][k] + ss[2][k] + ss[3][k]);
  } else {
    int k = threadIdx.x - D;
    atomicAdd(&sumsqP[slot + k], sq[0][k] + sq[1][k] + sq[2][k] + sq[3][k]);
  }
}

// ---------- BN stats from sliced partials; layer1 also folds t1 @ W2 ----------
__global__ void k_bnstats1(const float* __restrict__ sumP, const float* __restrict__ sumsqP,
                           const float* __restrict__ gamma, const float* __restrict__ beta,
                           const float* __restrict__ W2,
                           float* __restrict__ svec, float* __restrict__ tW2) {
  __shared__ float t[D];
  int k = threadIdx.x;
  float sm = 0.f, sq = 0.f;
  for (int i = 0; i < NSLOT; ++i) { sm += sumP[i * D + k]; sq += sumsqP[i * D + k]; }
  float mean = sm * (1.0f / NN);
  float var = sq * (1.0f / NN) - mean * mean;
  float s = gamma[k] * rsqrtf(var + BN_EPS);
  svec[k] = s;
  t[k] = beta[k] - mean * s;
  __syncthreads();
  float acc = 0.f;
  for (int kk = 0; kk < D; ++kk) acc += t[kk] * W2[kk * D + k];
  tW2[k] = acc;
}

__global__ void k_bnstats2(const float* __restrict__ sumP, const float* __restrict__ sumsqP,
                           const float* __restrict__ gamma, const float* __restrict__ beta,
                           float* __restrict__ svec, float* __restrict__ tvec) {
  int k = threadIdx.x;
  float sm = 0.f, sq = 0.f;
  for (int i = 0; i < NSLOT; ++i) { sm += sumP[i * D + k]; sq += sumsqP[i * D + k]; }
  float mean = sm * (1.0f / NN);
  float var = sq * (1.0f / NN) - mean * mean;
  float s = gamma[k] * rsqrtf(var + BN_EPS);
  svec[k] = s;
  tvec[k] = beta[k] - mean * s;
}

// ---------- head MLP ----------
__global__ __launch_bounds__(256) void k_head(const float* __restrict__ pooled, const float* __restrict__ s2,
                                              const float* __restrict__ t2, const float* __restrict__ Wp1,
                                              const float* __restrict__ bp1, const float* __restrict__ Wp2,
                                              const float* __restrict__ bp2, void* out,
                                              const int* __restrict__ flag) {
  __shared__ float y[D];
  __shared__ float wr[4];
  int g = blockIdx.x, j = threadIdx.x;
  if (j < D) y[j] = pooled[(size_t)g * D + j] * s2[j] + t2[j];
  __syncthreads();
  float acc = bp1[j];
#pragma unroll 4
  for (int k = 0; k < D; ++k) acc += y[k] * Wp1[k * DP + j];
  float v = fmaxf(acc, 0.f) * Wp2[j];
  for (int off = 32; off; off >>= 1) v += __shfl_down(v, off);
  if ((j & 63) == 0) wr[j >> 6] = v;
  __syncthreads();
  if (j == 0) {
    float r = wr[0] + wr[1] + wr[2] + wr[3] + bp2[0];
    if (flag[0]) ((bf16*)out)[g] = f2bf(r);
    else ((float*)out)[g] = r;
  }
}

extern "C" void kernel_launch(void* const* d_in, const int* in_sizes, int n_in,
                              void* d_out, int out_size, void* d_ws, size_t ws_size,
                              hipStream_t stream) {
  const void* x   = d_in[0];
  const int*  ei  = (const int*)d_in[1];
  const int*  bat = (const int*)d_in[2];

  float* f = (float*)d_ws;
  float* A = f; f += (size_t)NN * D;     // H1, then H2
  float* B = f; f += (size_t)NN * D;     // R1
  float* W1f  = f; f += D * D;
  float* W2f  = f; f += D * D;
  float* Wp1f = f; f += D * DP;
  float* b1f  = f; f += D;
  float* g1f  = f; f += D;
  float* be1f = f; f += D;
  float* b2f  = f; f += D;
  float* g2f  = f; f += D;
  float* be2f = f; f += D;
  float* bp1f = f; f += DP;
  float* Wp2f = f; f += DP;
  float* bp2f = f; f += 4;
  float* sum1P   = f; f += NSLOT * D;
  float* sumsq1P = f; f += NSLOT * D;
  float* sum2P   = f; f += NSLOT * D;
  float* sumsq2P = f; f += NSLOT * D;
  float* pooled = f; f += (size_t)NG * D;
  float* svec1  = f; f += D;
  float* tW2    = f; f += D;
  float* svec2  = f; f += D;
  float* tvec2  = f; f += D;
  float* isq    = f; f += NN;
  float* csr_c  = f; f += NE;
  int* csr_src = (int*)f; f += NE;
  int* ro      = (int*)f; f += NN + 1;
  int* cursor  = (int*)f; f += NN;
  int* cnt     = (int*)f; f += NN;
  int* flag    = (int*)f;

  hipMemsetAsync(cnt, 0, NN * sizeof(int), stream);
  hipMemsetAsync(sum1P, 0, (4 * NSLOT * D + NG * D) * sizeof(float), stream);

  k_detect<<<1, 64, 0, stream>>>((const unsigned short*)x, flag);

  CvtArgs ca;
  ca.s[0] = d_in[3];  ca.d[0] = W1f;  ca.n[0] = D * D;
  ca.s[1] = d_in[7];  ca.d[1] = W2f;  ca.n[1] = D * D;
  ca.s[2] = d_in[11]; ca.d[2] = Wp1f; ca.n[2] = D * DP;
  ca.s[3] = d_in[4];  ca.d[3] = b1f;  ca.n[3] = D;
  ca.s[4] = d_in[5];  ca.d[4] = g1f;  ca.n[4] = D;
  ca.s[5] = d_in[6];  ca.d[5] = be1f; ca.n[5] = D;
  ca.s[6] = d_in[8];  ca.d[6] = b2f;  ca.n[6] = D;
  ca.s[7] = d_in[9];  ca.d[7] = g2f;  ca.n[7] = D;
  ca.s[8] = d_in[10]; ca.d[8] = be2f; ca.n[8] = D;
  ca.s[9] = d_in[12]; ca.d[9] = bp1f; ca.n[9] = DP;
  ca.s[10] = d_in[13]; ca.d[10] = Wp2f; ca.n[10] = DP;
  ca.s[11] = d_in[14]; ca.d[11] = bp2f; ca.n[11] = 1;
  k_cvt<<<12, 256, 0, stream>>>(ca, flag);

  k_deg<<<(NE + 255) / 256, 256, 0, stream>>>(ei, cnt);
  k_scan<<<1, 1024, 0, stream>>>(cnt, ro, cursor);
  k_invd<<<(NN + 255) / 256, 256, 0, stream>>>(cnt, isq);
  k_fill<<<(NE + 255) / 256, 256, 0, stream>>>(ei, isq, cursor, csr_src, csr_c);

  // layer 1
  k_gemm<<<(NN + 31) / 32, 256, 0, stream>>>(x, flag, W1f, nullptr, nullptr, A, NN);
  k_agg<0><<<(NN + 15) / 16, 256, 0, stream>>>(A, ro, csr_src, csr_c, b1f, nullptr,
                                               B, sum1P, sumsq1P, nullptr);
  k_bnstats1<<<1, D, 0, stream>>>(sum1P, sumsq1P, g1f, be1f, W2f, svec1, tW2);

  // layer 2 (BN1 folded into GEMM via scale+rowadd)
  k_gemm<<<(NN + 31) / 32, 256, 0, stream>>>(B, nullptr, W2f, svec1, tW2, A, NN);
  k_agg<1><<<(NN + 15) / 16, 256, 0, stream>>>(A, ro, csr_src, csr_c, b2f, bat,
                                               nullptr, sum2P, sumsq2P, pooled);
  k_bnstats2<<<1, D, 0, stream>>>(sum2P, sumsq2P, g2f, be2f, svec2, tvec2);

  k_head<<<NG, DP, 0, stream>>>(pooled, svec2, tvec2, Wp1f, bp1f, Wp2f, bp2f, d_out, flag);
}

// Round 4
// 376.216 us; speedup vs baseline: 4.1922x; 1.4335x over previous
//
#include <hip/hip_runtime.h>

#define NN 50000
#define NE 800000
#define NG 64
#define D 128
#define DP 256
#define BN_EPS 1e-5f
#define NSLOT 32
#define NB 196  // ceil(NN/256)

typedef unsigned short bf16;

__device__ __forceinline__ float bf2f(unsigned h16) {
  unsigned u = (h16 & 0xffffu) << 16; float f; __builtin_memcpy(&f, &u, 4); return f;
}
__device__ __forceinline__ bf16 f2bf(float f) {
  unsigned u; __builtin_memcpy(&u, &f, 4);
  return (bf16)((u + 0x7FFFu + ((u >> 16) & 1u)) >> 16);
}
__device__ __forceinline__ unsigned packbf2(float a, float b) {
  return (unsigned)f2bf(a) | ((unsigned)f2bf(b) << 16);
}

// ---------- dtype detection: flag[0]=1 if bf16 input, flag[1]=1 const ----------
__global__ void k_detect(const unsigned short* __restrict__ x, int* __restrict__ flag) {
  if (threadIdx.x == 0) {
    int good = 0;
    for (int i = 0; i < 64; ++i) {
      float v = bf2f(x[2 * i]);
      float a = fabsf(v);
      if (v == 0.0f || (a > 1e-30f && a < 32.0f)) good++;
    }
    flag[0] = (good >= 56) ? 1 : 0;
    flag[1] = 1;
  }
}

// ---------- convert all weight tensors to f32 in ws ----------
struct CvtArgs {
  const void* s[12];
  float* d[12];
  int n[12];
};

__global__ __launch_bounds__(256) void k_cvt(CvtArgs a, const int* __restrict__ flag) {
  int t = blockIdx.x;
  int mode = flag[0];
  const void* sp = a.s[t];
  float* dp = a.d[t];
  int n = a.n[t];
  if (mode) {
    const unsigned short* s = (const unsigned short*)sp;
    for (int i = threadIdx.x; i < n; i += 256) dp[i] = bf2f(s[i]);
  } else {
    const float* s = (const float*)sp;
    for (int i = threadIdx.x; i < n; i += 256) dp[i] = s[i];
  }
}

// ---------- degree count ----------
__global__ __launch_bounds__(256) void k_deg(const int* __restrict__ ei, int* __restrict__ cnt) {
  int e = blockIdx.x * 256 + threadIdx.x;
  if (e < NE) atomicAdd(&cnt[ei[NE + e]], 1);
}

// ---------- scan stage 1: per-block sums ----------
__global__ __launch_bounds__(256) void k_bsum(const int* __restrict__ cnt, int* __restrict__ bsum) {
  int i = blockIdx.x * 256 + threadIdx.x;
  int v = (i < NN) ? cnt[i] : 0;
  __shared__ int s[4];
  for (int off = 32; off; off >>= 1) v += __shfl_down(v, off);
  if ((threadIdx.x & 63) == 0) s[threadIdx.x >> 6] = v;
  __syncthreads();
  if (threadIdx.x == 0) bsum[blockIdx.x] = s[0] + s[1] + s[2] + s[3];
}

// ---------- scan stage 2: exclusive scan of NB partials ----------
__global__ __launch_bounds__(256) void k_bscan(const int* __restrict__ bsum, int* __restrict__ bbase) {
  __shared__ int sh[256];
  int t = threadIdx.x;
  int v = (t < NB) ? bsum[t] : 0;
  sh[t] = v;
  __syncthreads();
  for (int off = 1; off < 256; off <<= 1) {
    int u = (t >= off) ? sh[t - off] : 0;
    __syncthreads();
    sh[t] += u;
    __syncthreads();
  }
  if (t < NB) bbase[t] = sh[t] - v;
}

// ---------- scan stage 3: per-element offsets + cursor + isq ----------
__global__ __launch_bounds__(256) void k_offsets(const int* __restrict__ cnt, const int* __restrict__ bbase,
                                                 int* __restrict__ ro, int* __restrict__ cursor,
                                                 float* __restrict__ isq) {
  __shared__ int sh[256];
  int t = threadIdx.x;
  int i = blockIdx.x * 256 + t;
  int c = (i < NN) ? cnt[i] : 0;
  sh[t] = c;
  __syncthreads();
  for (int off = 1; off < 256; off <<= 1) {
    int u = (t >= off) ? sh[t - off] : 0;
    __syncthreads();
    sh[t] += u;
    __syncthreads();
  }
  if (i < NN) {
    int o = bbase[blockIdx.x] + sh[t] - c;
    ro[i] = o; cursor[i] = o;
    isq[i] = rsqrtf((float)(c + 1));
  }
  if (i == 0) ro[NN] = NE;
}

// ---------- fill CSR: csr_src[slot], csr_c[slot] = isq[s]*isq[d] ----------
__global__ __launch_bounds__(256) void k_fill(const int* __restrict__ ei, const float* __restrict__ isq,
                                              int* __restrict__ cursor,
                                              int* __restrict__ csr_src, float* __restrict__ csr_c) {
  int e = blockIdx.x * 256 + threadIdx.x;
  if (e < NE) {
    int s = ei[e], d = ei[NE + e];
    int slot = atomicAdd(&cursor[d], 1);
    csr_src[slot] = s;
    csr_c[slot] = isq[s] * isq[d];
  }
}

// ---------- GEMM: Out[n][j] = sum_k X[n][k]*(scale?s[k]:1)*W[k][j] + (rowadd?ra[j]:0) ----------
// X dtype: flag null -> f32, else flag[idx]=1 -> bf16. Output: bf16.
__global__ __launch_bounds__(256) void k_gemm(const void* Xv, const int* __restrict__ flag,
                                              const float* __restrict__ W,
                                              const float* __restrict__ scale,
                                              const float* __restrict__ rowadd,
                                              bf16* __restrict__ Out, int nrows) {
  __shared__ float Wl[D * D];      // 64 KB
  __shared__ float Xs[32][D];      // 16 KB
  int mode = flag ? flag[0] : 0;
  for (int i = threadIdx.x; i < D * D / 4; i += 256) {
    float4 w = ((const float4*)W)[i];
    float sc = scale ? scale[i >> 5] : 1.0f;
    ((float4*)Wl)[i] = make_float4(w.x * sc, w.y * sc, w.z * sc, w.w * sc);
  }
  int jg = threadIdx.x & 31, rg = threadIdx.x >> 5;
  float4 rav = make_float4(0.f, 0.f, 0.f, 0.f);
  if (rowadd) rav = ((const float4*)rowadd)[jg];
  for (int tile = blockIdx.x * 32; tile < nrows; tile += gridDim.x * 32) {
    int rows = min(32, nrows - tile);
    __syncthreads();
    if (mode) {
      const bf16* X = (const bf16*)Xv;
      for (int i = threadIdx.x; i < rows * (D / 8); i += 256) {
        int r = i >> 4, c8 = i & 15;
        uint4 raw = ((const uint4*)(X + (size_t)(tile + r) * D))[c8];
        float* xp = &Xs[r][c8 * 8];
        xp[0] = bf2f(raw.x & 0xffff); xp[1] = bf2f(raw.x >> 16);
        xp[2] = bf2f(raw.y & 0xffff); xp[3] = bf2f(raw.y >> 16);
        xp[4] = bf2f(raw.z & 0xffff); xp[5] = bf2f(raw.z >> 16);
        xp[6] = bf2f(raw.w & 0xffff); xp[7] = bf2f(raw.w >> 16);
      }
    } else {
      const float* X = (const float*)Xv;
      for (int i = threadIdx.x; i < rows * (D / 4); i += 256) {
        int r = i >> 5, c = i & 31;
        ((float4*)Xs[r])[c] = ((const float4*)(X + (size_t)(tile + r) * D))[c];
      }
    }
    __syncthreads();
    float4 a0 = rav, a1 = rav, a2 = rav, a3 = rav;
#pragma unroll 4
    for (int k = 0; k < D; ++k) {
      float4 wv = ((float4*)&Wl[k * D])[jg];
      float x0 = Xs[rg * 4 + 0][k], x1 = Xs[rg * 4 + 1][k];
      float x2 = Xs[rg * 4 + 2][k], x3 = Xs[rg * 4 + 3][k];
      a0.x += x0 * wv.x; a0.y += x0 * wv.y; a0.z += x0 * wv.z; a0.w += x0 * wv.w;
      a1.x += x1 * wv.x; a1.y += x1 * wv.y; a1.z += x1 * wv.z; a1.w += x1 * wv.w;
      a2.x += x2 * wv.x; a2.y += x2 * wv.y; a2.z += x2 * wv.z; a2.w += x2 * wv.w;
      a3.x += x3 * wv.x; a3.y += x3 * wv.y; a3.z += x3 * wv.z; a3.w += x3 * wv.w;
    }
    int r0 = tile + rg * 4;
    if (r0 + 0 < nrows) ((uint2*)(Out + (size_t)(r0 + 0) * D))[jg] = make_uint2(packbf2(a0.x, a0.y), packbf2(a0.z, a0.w));
    if (r0 + 1 < nrows) ((uint2*)(Out + (size_t)(r0 + 1) * D))[jg] = make_uint2(packbf2(a1.x, a1.y), packbf2(a1.z, a1.w));
    if (r0 + 2 < nrows) ((uint2*)(Out + (size_t)(r0 + 2) * D))[jg] = make_uint2(packbf2(a2.x, a2.y), packbf2(a2.z, a2.w));
    if (r0 + 3 < nrows) ((uint2*)(Out + (size_t)(r0 + 3) * D))[jg] = make_uint2(packbf2(a3.x, a3.y), packbf2(a3.z, a3.w));
  }
}

// ---------- CSR aggregation + fused epilogue (H in bf16) ----------
// wave handles 4 nodes; lane owns columns (2*lane, 2*lane+1).
template <int LAYER2>
__global__ __launch_bounds__(256) void k_agg(const bf16* __restrict__ H, const int* __restrict__ ro,
                                             const int* __restrict__ csr_src, const float* __restrict__ csr_c,
                                             const float* __restrict__ b, const int* __restrict__ batch,
                                             bf16* __restrict__ Rout,
                                             float* __restrict__ sumP, float* __restrict__ sumsqP,
                                             float* __restrict__ pooled) {
  int lane = threadIdx.x & 63, w = threadIdx.x >> 6;
  int nbase = blockIdx.x * 16 + w * 4;
  float2 bv = ((const float2*)b)[lane];
  float2 ls = make_float2(0.f, 0.f), lq = make_float2(0.f, 0.f);
  int gcur = -1; float2 mx = make_float2(0.f, 0.f);
  int nend = min(nbase + 4, NN);
  for (int n = nbase; n < nend; ++n) {
    int r0 = ro[n], r1 = ro[n + 1];
    float invd = 1.0f / (float)(r1 - r0 + 1);
    unsigned hv = ((const unsigned*)(H + (size_t)n * D))[lane];
    float2 acc = make_float2(bf2f(hv & 0xffff) * invd, bf2f(hv >> 16) * invd);
    int e = r0;
    for (; e + 2 <= r1; e += 2) {
      int s0 = csr_src[e], s1 = csr_src[e + 1];
      float c0 = csr_c[e], c1 = csr_c[e + 1];
      unsigned xa = ((const unsigned*)(H + (size_t)s0 * D))[lane];
      unsigned xb = ((const unsigned*)(H + (size_t)s1 * D))[lane];
      acc.x += bf2f(xa & 0xffff) * c0; acc.y += bf2f(xa >> 16) * c0;
      acc.x += bf2f(xb & 0xffff) * c1; acc.y += bf2f(xb >> 16) * c1;
    }
    if (e < r1) {
      int s0 = csr_src[e];
      float c0 = csr_c[e];
      unsigned xa = ((const unsigned*)(H + (size_t)s0 * D))[lane];
      acc.x += bf2f(xa & 0xffff) * c0; acc.y += bf2f(xa >> 16) * c0;
    }
    float2 r = make_float2(fmaxf(acc.x + bv.x, 0.f), fmaxf(acc.y + bv.y, 0.f));
    if (!LAYER2) ((unsigned*)(Rout + (size_t)n * D))[lane] = packbf2(r.x, r.y);
    ls.x += r.x; ls.y += r.y; lq.x += r.x * r.x; lq.y += r.y * r.y;
    if (LAYER2) {
      int g = batch[n];
      if (g != gcur) {
        if (gcur >= 0) {
          atomicMax((int*)&pooled[(size_t)gcur * D + 2 * lane], __float_as_int(mx.x));
          atomicMax((int*)&pooled[(size_t)gcur * D + 2 * lane + 1], __float_as_int(mx.y));
        }
        gcur = g; mx = make_float2(0.f, 0.f);
      }
      mx.x = fmaxf(mx.x, r.x); mx.y = fmaxf(mx.y, r.y);
    }
  }
  if (LAYER2 && gcur >= 0) {
    atomicMax((int*)&pooled[(size_t)gcur * D + 2 * lane], __float_as_int(mx.x));
    atomicMax((int*)&pooled[(size_t)gcur * D + 2 * lane + 1], __float_as_int(mx.y));
  }
  __shared__ float ss[4][D], sq[4][D];
  ss[w][2 * lane] = ls.x; ss[w][2 * lane + 1] = ls.y;
  sq[w][2 * lane] = lq.x; sq[w][2 * lane + 1] = lq.y;
  __syncthreads();
  int slot = (blockIdx.x & (NSLOT - 1)) * D;
  if (threadIdx.x < D) {
    int k = threadIdx.x;
    atomicAdd(&sumP[slot + k], ss[0][k] + ss[1][k] + ss[2][k] + ss[3][k]);
  } else {
    int k = threadIdx.x - D;
    atomicAdd(&sumsqP[slot + k], sq[0][k] + sq[1][k] + sq[2][k] + sq[3][k]);
  }
}

// ---------- BN stats from sliced partials; layer1 also folds t1 @ W2 ----------
__global__ void k_bnstats1(const float* __restrict__ sumP, const float* __restrict__ sumsqP,
                           const float* __restrict__ gamma, const float* __restrict__ beta,
                           const float* __restrict__ W2,
                           float* __restrict__ svec, float* __restrict__ tW2) {
  __shared__ float t[D];
  int k = threadIdx.x;
  float sm = 0.f, sq = 0.f;
  for (int i = 0; i < NSLOT; ++i) { sm += sumP[i * D + k]; sq += sumsqP[i * D + k]; }
  float mean = sm * (1.0f / NN);
  float var = sq * (1.0f / NN) - mean * mean;
  float s = gamma[k] * rsqrtf(var + BN_EPS);
  svec[k] = s;
  t[k] = beta[k] - mean * s;
  __syncthreads();
  float acc = 0.f;
  for (int kk = 0; kk < D; ++kk) acc += t[kk] * W2[kk * D + k];
  tW2[k] = acc;
}

__global__ void k_bnstats2(const float* __restrict__ sumP, const float* __restrict__ sumsqP,
                           const float* __restrict__ gamma, const float* __restrict__ beta,
                           float* __restrict__ svec, float* __restrict__ tvec) {
  int k = threadIdx.x;
  float sm = 0.f, sq = 0.f;
  for (int i = 0; i < NSLOT; ++i) { sm += sumP[i * D + k]; sq += sumsqP[i * D + k]; }
  float mean = sm * (1.0f / NN);
  float var = sq * (1.0f / NN) - mean * mean;
  float s = gamma[k] * rsqrtf(var + BN_EPS);
  svec[k] = s;
  tvec[k] = beta[k] - mean * s;
}

// ---------- head MLP ----------
__global__ __launch_bounds__(256) void k_head(const float* __restrict__ pooled, const float* __restrict__ s2,
                                              const float* __restrict__ t2, const float* __restrict__ Wp1,
                                              const float* __restrict__ bp1, const float* __restrict__ Wp2,
                                              const float* __restrict__ bp2, void* out,
                                              const int* __restrict__ flag) {
  __shared__ float y[D];
  __shared__ float wr[4];
  int g = blockIdx.x, j = threadIdx.x;
  if (j < D) y[j] = pooled[(size_t)g * D + j] * s2[j] + t2[j];
  __syncthreads();
  float acc = bp1[j];
#pragma unroll 4
  for (int k = 0; k < D; ++k) acc += y[k] * Wp1[k * DP + j];
  float v = fmaxf(acc, 0.f) * Wp2[j];
  for (int off = 32; off; off >>= 1) v += __shfl_down(v, off);
  if ((j & 63) == 0) wr[j >> 6] = v;
  __syncthreads();
  if (j == 0) {
    float r = wr[0] + wr[1] + wr[2] + wr[3] + bp2[0];
    if (flag[0]) ((bf16*)out)[g] = f2bf(r);
    else ((float*)out)[g] = r;
  }
}

extern "C" void kernel_launch(void* const* d_in, const int* in_sizes, int n_in,
                              void* d_out, int out_size, void* d_ws, size_t ws_size,
                              hipStream_t stream) {
  const void* x   = d_in[0];
  const int*  ei  = (const int*)d_in[1];
  const int*  bat = (const int*)d_in[2];

  float* f = (float*)d_ws;
  bf16* A = (bf16*)f; f += (size_t)NN * D / 2;   // H1, then H2 (bf16)
  bf16* B = (bf16*)f; f += (size_t)NN * D / 2;   // R1 (bf16)
  float* W1f  = f; f += D * D;
  float* W2f  = f; f += D * D;
  float* Wp1f = f; f += D * DP;
  float* b1f  = f; f += D;
  float* g1f  = f; f += D;
  float* be1f = f; f += D;
  float* b2f  = f; f += D;
  float* g2f  = f; f += D;
  float* be2f = f; f += D;
  float* bp1f = f; f += DP;
  float* Wp2f = f; f += DP;
  float* bp2f = f; f += 4;
  float* sum1P   = f; f += NSLOT * D;
  float* sumsq1P = f; f += NSLOT * D;
  float* sum2P   = f; f += NSLOT * D;
  float* sumsq2P = f; f += NSLOT * D;
  float* pooled = f; f += (size_t)NG * D;
  float* svec1  = f; f += D;
  float* tW2    = f; f += D;
  float* svec2  = f; f += D;
  float* tvec2  = f; f += D;
  float* isq    = f; f += NN;
  float* csr_c  = f; f += NE;
  int* csr_src = (int*)f; f += NE;
  int* ro      = (int*)f; f += NN + 1;
  int* cursor  = (int*)f; f += NN;
  int* cnt     = (int*)f; f += NN;
  int* bsum    = (int*)f; f += NB;
  int* bbase   = (int*)f; f += NB;
  int* flag    = (int*)f;

  hipMemsetAsync(cnt, 0, NN * sizeof(int), stream);
  hipMemsetAsync(sum1P, 0, (4 * NSLOT * D + NG * D) * sizeof(float), stream);

  k_detect<<<1, 64, 0, stream>>>((const unsigned short*)x, flag);

  CvtArgs ca;
  ca.s[0] = d_in[3];  ca.d[0] = W1f;  ca.n[0] = D * D;
  ca.s[1] = d_in[7];  ca.d[1] = W2f;  ca.n[1] = D * D;
  ca.s[2] = d_in[11]; ca.d[2] = Wp1f; ca.n[2] = D * DP;
  ca.s[3] = d_in[4];  ca.d[3] = b1f;  ca.n[3] = D;
  ca.s[4] = d_in[5];  ca.d[4] = g1f;  ca.n[4] = D;
  ca.s[5] = d_in[6];  ca.d[5] = be1f; ca.n[5] = D;
  ca.s[6] = d_in[8];  ca.d[6] = b2f;  ca.n[6] = D;
  ca.s[7] = d_in[9];  ca.d[7] = g2f;  ca.n[7] = D;
  ca.s[8] = d_in[10]; ca.d[8] = be2f; ca.n[8] = D;
  ca.s[9] = d_in[12]; ca.d[9] = bp1f; ca.n[9] = DP;
  ca.s[10] = d_in[13]; ca.d[10] = Wp2f; ca.n[10] = DP;
  ca.s[11] = d_in[14]; ca.d[11] = bp2f; ca.n[11] = 1;
  k_cvt<<<12, 256, 0, stream>>>(ca, flag);

  k_deg<<<(NE + 255) / 256, 256, 0, stream>>>(ei, cnt);
  k_bsum<<<NB, 256, 0, stream>>>(cnt, bsum);
  k_bscan<<<1, 256, 0, stream>>>(bsum, bbase);
  k_offsets<<<NB, 256, 0, stream>>>(cnt, bbase, ro, cursor, isq);
  k_fill<<<(NE + 255) / 256, 256, 0, stream>>>(ei, isq, cursor, csr_src, csr_c);

  // layer 1
  k_gemm<<<(NN + 31) / 32, 256, 0, stream>>>(x, flag, W1f, nullptr, nullptr, A, NN);
  k_agg<0><<<(NN + 15) / 16, 256, 0, stream>>>(A, ro, csr_src, csr_c, b1f, nullptr,
                                               B, sum1P, sumsq1P, nullptr);
  k_bnstats1<<<1, D, 0, stream>>>(sum1P, sumsq1P, g1f, be1f, W2f, svec1, tW2);

  // layer 2 (BN1 folded into GEMM via scale+rowadd; R1 is bf16 -> flag+1 path)
  k_gemm<<<(NN + 31) / 32, 256, 0, stream>>>(B, flag + 1, W2f, svec1, tW2, A, NN);
  k_agg<1><<<(NN + 15) / 16, 256, 0, stream>>>(A, ro, csr_src, csr_c, b2f, bat,
                                               nullptr, sum2P, sumsq2P, pooled);
  k_bnstats2<<<1, D, 0, stream>>>(sum2P, sumsq2P, g2f, be2f, svec2, tvec2);

  k_head<<<NG, DP, 0, stream>>>(pooled, svec2, tvec2, Wp1f, bp1f, Wp2f, bp2f, d_out, flag);
}

// Round 5
// 376.201 us; speedup vs baseline: 4.1923x; 1.0000x over previous
//
#include <hip/hip_runtime.h>

#define NN 50000
#define NE 800000
#define NG 64
#define D 128
#define DP 256
#define BN_EPS 1e-5f
#define NSLOT 32
#define NB 196  // ceil(NN/256)

typedef unsigned short bf16;
typedef __attribute__((ext_vector_type(8))) short s16x8;
typedef __attribute__((ext_vector_type(4))) float f32x4;

__device__ __forceinline__ float bf2f(unsigned h16) {
  unsigned u = (h16 & 0xffffu) << 16; float f; __builtin_memcpy(&f, &u, 4); return f;
}
__device__ __forceinline__ bf16 f2bf(float f) {
  unsigned u; __builtin_memcpy(&u, &f, 4);
  return (bf16)((u + 0x7FFFu + ((u >> 16) & 1u)) >> 16);
}
__device__ __forceinline__ unsigned packbf2(float a, float b) {
  return (unsigned)f2bf(a) | ((unsigned)f2bf(b) << 16);
}
__device__ __forceinline__ s16x8 u4cast(uint4 v) {
  s16x8 r; __builtin_memcpy(&r, &v, 16); return r;
}

// ---------- dtype detection: flag[0]=1 if bf16 input, flag[1]=1 const ----------
__global__ void k_detect(const unsigned short* __restrict__ x, int* __restrict__ flag) {
  if (threadIdx.x == 0) {
    int good = 0;
    for (int i = 0; i < 64; ++i) {
      float v = bf2f(x[2 * i]);
      float a = fabsf(v);
      if (v == 0.0f || (a > 1e-30f && a < 32.0f)) good++;
    }
    flag[0] = (good >= 56) ? 1 : 0;
    flag[1] = 1;
  }
}

// ---------- convert all weight tensors to f32 in ws ----------
struct CvtArgs {
  const void* s[12];
  float* d[12];
  int n[12];
};

__global__ __launch_bounds__(256) void k_cvt(CvtArgs a, const int* __restrict__ flag) {
  int t = blockIdx.x;
  int mode = flag[0];
  const void* sp = a.s[t];
  float* dp = a.d[t];
  int n = a.n[t];
  if (mode) {
    const unsigned short* s = (const unsigned short*)sp;
    for (int i = threadIdx.x; i < n; i += 256) dp[i] = bf2f(s[i]);
  } else {
    const float* s = (const float*)sp;
    for (int i = threadIdx.x; i < n; i += 256) dp[i] = s[i];
  }
}

// ---------- degree count ----------
__global__ __launch_bounds__(256) void k_deg(const int* __restrict__ ei, int* __restrict__ cnt) {
  int e = blockIdx.x * 256 + threadIdx.x;
  if (e < NE) atomicAdd(&cnt[ei[NE + e]], 1);
}

// ---------- scan stage 1: per-block sums ----------
__global__ __launch_bounds__(256) void k_bsum(const int* __restrict__ cnt, int* __restrict__ bsum) {
  int i = blockIdx.x * 256 + threadIdx.x;
  int v = (i < NN) ? cnt[i] : 0;
  __shared__ int s[4];
  for (int off = 32; off; off >>= 1) v += __shfl_down(v, off);
  if ((threadIdx.x & 63) == 0) s[threadIdx.x >> 6] = v;
  __syncthreads();
  if (threadIdx.x == 0) bsum[blockIdx.x] = s[0] + s[1] + s[2] + s[3];
}

// ---------- scan stage 2: exclusive scan of NB partials ----------
__global__ __launch_bounds__(256) void k_bscan(const int* __restrict__ bsum, int* __restrict__ bbase) {
  __shared__ int sh[256];
  int t = threadIdx.x;
  int v = (t < NB) ? bsum[t] : 0;
  sh[t] = v;
  __syncthreads();
  for (int off = 1; off < 256; off <<= 1) {
    int u = (t >= off) ? sh[t - off] : 0;
    __syncthreads();
    sh[t] += u;
    __syncthreads();
  }
  if (t < NB) bbase[t] = sh[t] - v;
}

// ---------- scan stage 3: per-element offsets + cursor + isq ----------
__global__ __launch_bounds__(256) void k_offsets(const int* __restrict__ cnt, const int* __restrict__ bbase,
                                                 int* __restrict__ ro, int* __restrict__ cursor,
                                                 float* __restrict__ isq) {
  __shared__ int sh[256];
  int t = threadIdx.x;
  int i = blockIdx.x * 256 + t;
  int c = (i < NN) ? cnt[i] : 0;
  sh[t] = c;
  __syncthreads();
  for (int off = 1; off < 256; off <<= 1) {
    int u = (t >= off) ? sh[t - off] : 0;
    __syncthreads();
    sh[t] += u;
    __syncthreads();
  }
  if (i < NN) {
    int o = bbase[blockIdx.x] + sh[t] - c;
    ro[i] = o; cursor[i] = o;
    isq[i] = rsqrtf((float)(c + 1));
  }
  if (i == 0) ro[NN] = NE;
}

// ---------- fill CSR: pk[slot] = {src, bits(isq[s]*isq[d])} ----------
__global__ __launch_bounds__(256) void k_fill(const int* __restrict__ ei, const float* __restrict__ isq,
                                              int* __restrict__ cursor, int2* __restrict__ pk) {
  int e = blockIdx.x * 256 + threadIdx.x;
  if (e < NE) {
    int s = ei[e], d = ei[NE + e];
    int slot = atomicAdd(&cursor[d], 1);
    int2 v; v.x = s; v.y = __float_as_int(isq[s] * isq[d]);
    pk[slot] = v;
  }
}

// ---------- pack W (f32 [D][D], optional row-scale by scale[k]) into MFMA B-frag layout ----------
// slot = ((kc*8 + ct)*64 + lane); element j = W[kc*32 + (lane>>4)*8 + j][ct*16 + (lane&15)]
__global__ __launch_bounds__(256) void k_pack(const float* __restrict__ W, const float* __restrict__ scale,
                                              bf16* __restrict__ Wp) {
  int slot = blockIdx.x * 256 + threadIdx.x;
  if (slot >= 2048) return;
  int kc = slot >> 9, ct = (slot >> 6) & 7, l = slot & 63;
  int q = l >> 4, p = l & 15;
  int n = ct * 16 + p;
  unsigned u[4];
#pragma unroll
  for (int jj = 0; jj < 4; ++jj) {
    int k0 = kc * 32 + q * 8 + jj * 2;
    float w0 = W[k0 * D + n], w1 = W[(k0 + 1) * D + n];
    if (scale) { w0 *= scale[k0]; w1 *= scale[k0 + 1]; }
    u[jj] = packbf2(w0, w1);
  }
  uint4 o = make_uint4(u[0], u[1], u[2], u[3]);
  *(uint4*)(Wp + (size_t)slot * 8) = o;
}

// ---------- MFMA GEMM: Out[n][:] = X[n][:] @ Wpacked + (rowadd?:0), bf16 out ----------
// 256 thr = 4 waves; wave owns 16 rows x 128 cols; K=128 in 4 chunks of 32.
__global__ __launch_bounds__(256) void k_mgemm(const void* __restrict__ Xv, const int* __restrict__ flag,
                                               const bf16* __restrict__ Wp,
                                               const float* __restrict__ rowadd,
                                               bf16* __restrict__ Out, int nrows) {
  __shared__ float Cs[4][16][D + 4];   // pad 4 floats: breaks 4-way write conflict, keeps 16B align
  int l = threadIdx.x & 63, w = threadIdx.x >> 6;
  int q = l >> 4, p = l & 15;
  int mode = flag ? flag[0] : 0;
  float rv[8];
#pragma unroll
  for (int ct = 0; ct < 8; ++ct) rv[ct] = rowadd ? rowadd[ct * 16 + p] : 0.f;
  int ntiles = (nrows + 63) >> 6;
  for (int t = blockIdx.x; t < ntiles; t += gridDim.x) {
    int wb = t * 64 + w * 16;
    int rowc = min(wb + p, nrows - 1);
    f32x4 acc[8];
#pragma unroll
    for (int ct = 0; ct < 8; ++ct) { f32x4 z = {rv[ct], rv[ct], rv[ct], rv[ct]}; acc[ct] = z; }
#pragma unroll
    for (int kc = 0; kc < 4; ++kc) {
      s16x8 a;
      if (mode) {
        uint4 av = *(const uint4*)((const bf16*)Xv + (size_t)rowc * D + kc * 32 + q * 8);
        a = u4cast(av);
      } else {
        const float* Xf = (const float*)Xv + (size_t)rowc * D + kc * 32 + q * 8;
        float4 f0 = *(const float4*)Xf;
        float4 f1 = *(const float4*)(Xf + 4);
        uint4 u = make_uint4(packbf2(f0.x, f0.y), packbf2(f0.z, f0.w),
                             packbf2(f1.x, f1.y), packbf2(f1.z, f1.w));
        a = u4cast(u);
      }
#pragma unroll
      for (int ct = 0; ct < 8; ++ct) {
        s16x8 bfr = *(const s16x8*)(Wp + (size_t)(((kc << 3) + ct) * 64 + l) * 8);
        acc[ct] = __builtin_amdgcn_mfma_f32_16x16x32_bf16(a, bfr, acc[ct], 0, 0, 0);
      }
    }
#pragma unroll
    for (int ct = 0; ct < 8; ++ct)
#pragma unroll
      for (int r = 0; r < 4; ++r)
        Cs[w][q * 4 + r][ct * 16 + p] = acc[ct][r];
    __syncthreads();
#pragma unroll
    for (int i = 0; i < 4; ++i) {
      int idx = i * 64 + l;
      int rr = idx >> 4, c8 = idx & 15;
      int gr = t * 64 + w * 16 + rr;
      if (gr < nrows) {
        float4 v0 = *(const float4*)&Cs[w][rr][c8 * 8];
        float4 v1 = *(const float4*)&Cs[w][rr][c8 * 8 + 4];
        uint4 o = make_uint4(packbf2(v0.x, v0.y), packbf2(v0.z, v0.w),
                             packbf2(v1.x, v1.y), packbf2(v1.z, v1.w));
        *(uint4*)(Out + (size_t)gr * D + c8 * 8) = o;
      }
    }
    __syncthreads();
  }
}

// ---------- CSR aggregation + fused epilogue (H bf16) ----------
// wave = 4 quads of 16 lanes; quad gathers a full 256B row per edge (16B/lane);
// wave processes 4 nodes; quad-partials merged by shfl_xor butterfly.
#define ACC4(hx, cc)                                            \
  acc[0] += bf2f(hx.x & 0xffff) * cc; acc[1] += bf2f(hx.x >> 16) * cc; \
  acc[2] += bf2f(hx.y & 0xffff) * cc; acc[3] += bf2f(hx.y >> 16) * cc; \
  acc[4] += bf2f(hx.z & 0xffff) * cc; acc[5] += bf2f(hx.z >> 16) * cc; \
  acc[6] += bf2f(hx.w & 0xffff) * cc; acc[7] += bf2f(hx.w >> 16) * cc;

template <int LAYER2>
__global__ __launch_bounds__(256) void k_agg(const bf16* __restrict__ H, const int* __restrict__ ro,
                                             const int2* __restrict__ pk,
                                             const float* __restrict__ b, const int* __restrict__ batch,
                                             bf16* __restrict__ Rout,
                                             float* __restrict__ sumP, float* __restrict__ sumsqP,
                                             float* __restrict__ pooled) {
  int l = threadIdx.x & 63, w = threadIdx.x >> 6;
  int q = l >> 4, p = l & 15;
  float4 bv0 = ((const float4*)b)[p * 2], bv1 = ((const float4*)b)[p * 2 + 1];
  float bv[8] = {bv0.x, bv0.y, bv0.z, bv0.w, bv1.x, bv1.y, bv1.z, bv1.w};
  float ls[8], lq[8], mx[8];
#pragma unroll
  for (int j = 0; j < 8; ++j) { ls[j] = 0.f; lq[j] = 0.f; mx[j] = 0.f; }
  int gcur = -1;
  int nbase = blockIdx.x * 16 + w * 4;
  int nend = min(nbase + 4, NN);
  for (int n = nbase; n < nend; ++n) {
    int r0 = ro[n], r1 = ro[n + 1];
    float invd = 1.0f / (float)(r1 - r0 + 1);
    float acc[8];
#pragma unroll
    for (int j = 0; j < 8; ++j) acc[j] = 0.f;
    int e = r0 + q;
    for (; e + 4 < r1; e += 8) {
      int2 pa = pk[e], pb = pk[e + 4];
      float ca = __int_as_float(pa.y), cb = __int_as_float(pb.y);
      uint4 ha = *(const uint4*)(H + (size_t)pa.x * D + p * 8);
      uint4 hb = *(const uint4*)(H + (size_t)pb.x * D + p * 8);
      ACC4(ha, ca)
      ACC4(hb, cb)
    }
    if (e < r1) {
      int2 pa = pk[e];
      float ca = __int_as_float(pa.y);
      uint4 ha = *(const uint4*)(H + (size_t)pa.x * D + p * 8);
      ACC4(ha, ca)
    }
#pragma unroll
    for (int j = 0; j < 8; ++j) acc[j] += __shfl_xor(acc[j], 16);
#pragma unroll
    for (int j = 0; j < 8; ++j) acc[j] += __shfl_xor(acc[j], 32);
    uint4 hn = *(const uint4*)(H + (size_t)n * D + p * 8);
    float acs[8];
    acs[0] = bf2f(hn.x & 0xffff); acs[1] = bf2f(hn.x >> 16);
    acs[2] = bf2f(hn.y & 0xffff); acs[3] = bf2f(hn.y >> 16);
    acs[4] = bf2f(hn.z & 0xffff); acs[5] = bf2f(hn.z >> 16);
    acs[6] = bf2f(hn.w & 0xffff); acs[7] = bf2f(hn.w >> 16);
    float r[8];
#pragma unroll
    for (int j = 0; j < 8; ++j) {
      r[j] = fmaxf(acc[j] + acs[j] * invd + bv[j], 0.f);
      ls[j] += r[j]; lq[j] += r[j] * r[j];
    }
    if (!LAYER2 && q == 0) {
      uint4 o = make_uint4(packbf2(r[0], r[1]), packbf2(r[2], r[3]),
                           packbf2(r[4], r[5]), packbf2(r[6], r[7]));
      *(uint4*)(Rout + (size_t)n * D + p * 8) = o;
    }
    if (LAYER2) {
      int g = batch[n];
      if (g != gcur) {
        if (gcur >= 0 && q == 0) {
#pragma unroll
          for (int j = 0; j < 8; ++j)
            atomicMax((int*)&pooled[(size_t)gcur * D + p * 8 + j], __float_as_int(mx[j]));
        }
        gcur = g;
#pragma unroll
        for (int j = 0; j < 8; ++j) mx[j] = 0.f;
      }
#pragma unroll
      for (int j = 0; j < 8; ++j) mx[j] = fmaxf(mx[j], r[j]);
    }
  }
  if (LAYER2 && gcur >= 0 && q == 0) {
#pragma unroll
    for (int j = 0; j < 8; ++j)
      atomicMax((int*)&pooled[(size_t)gcur * D + p * 8 + j], __float_as_int(mx[j]));
  }
  __shared__ float ss[4][D], sq[4][D];
  if (q == 0) {
#pragma unroll
    for (int j = 0; j < 8; ++j) { ss[w][p * 8 + j] = ls[j]; sq[w][p * 8 + j] = lq[j]; }
  }
  __syncthreads();
  int slot = (blockIdx.x & (NSLOT - 1)) * D;
  if (threadIdx.x < D) {
    int k = threadIdx.x;
    atomicAdd(&sumP[slot + k], ss[0][k] + ss[1][k] + ss[2][k] + ss[3][k]);
  } else {
    int k = threadIdx.x - D;
    atomicAdd(&sumsqP[slot + k], sq[0][k] + sq[1][k] + sq[2][k] + sq[3][k]);
  }
}

// ---------- BN stats from sliced partials; layer1 also folds t1 @ W2 ----------
__global__ void k_bnstats1(const float* __restrict__ sumP, const float* __restrict__ sumsqP,
                           const float* __restrict__ gamma, const float* __restrict__ beta,
                           const float* __restrict__ W2,
                           float* __restrict__ svec, float* __restrict__ tW2) {
  __shared__ float t[D];
  int k = threadIdx.x;
  float sm = 0.f, sq = 0.f;
  for (int i = 0; i < NSLOT; ++i) { sm += sumP[i * D + k]; sq += sumsqP[i * D + k]; }
  float mean = sm * (1.0f / NN);
  float var = sq * (1.0f / NN) - mean * mean;
  float s = gamma[k] * rsqrtf(var + BN_EPS);
  svec[k] = s;
  t[k] = beta[k] - mean * s;
  __syncthreads();
  float acc = 0.f;
  for (int kk = 0; kk < D; ++kk) acc += t[kk] * W2[kk * D + k];
  tW2[k] = acc;
}

__global__ void k_bnstats2(const float* __restrict__ sumP, const float* __restrict__ sumsqP,
                           const float* __restrict__ gamma, const float* __restrict__ beta,
                           float* __restrict__ svec, float* __restrict__ tvec) {
  int k = threadIdx.x;
  float sm = 0.f, sq = 0.f;
  for (int i = 0; i < NSLOT; ++i) { sm += sumP[i * D + k]; sq += sumsqP[i * D + k]; }
  float mean = sm * (1.0f / NN);
  float var = sq * (1.0f / NN) - mean * mean;
  float s = gamma[k] * rsqrtf(var + BN_EPS);
  svec[k] = s;
  tvec[k] = beta[k] - mean * s;
}

// ---------- head MLP ----------
__global__ __launch_bounds__(256) void k_head(const float* __restrict__ pooled, const float* __restrict__ s2,
                                              const float* __restrict__ t2, const float* __restrict__ Wp1,
                                              const float* __restrict__ bp1, const float* __restrict__ Wp2,
                                              const float* __restrict__ bp2, void* out,
                                              const int* __restrict__ flag) {
  __shared__ float y[D];
  __shared__ float wr[4];
  int g = blockIdx.x, j = threadIdx.x;
  if (j < D) y[j] = pooled[(size_t)g * D + j] * s2[j] + t2[j];
  __syncthreads();
  float acc = bp1[j];
#pragma unroll 4
  for (int k = 0; k < D; ++k) acc += y[k] * Wp1[k * DP + j];
  float v = fmaxf(acc, 0.f) * Wp2[j];
  for (int off = 32; off; off >>= 1) v += __shfl_down(v, off);
  if ((j & 63) == 0) wr[j >> 6] = v;
  __syncthreads();
  if (j == 0) {
    float r = wr[0] + wr[1] + wr[2] + wr[3] + bp2[0];
    if (flag[0]) ((bf16*)out)[g] = f2bf(r);
    else ((float*)out)[g] = r;
  }
}

extern "C" void kernel_launch(void* const* d_in, const int* in_sizes, int n_in,
                              void* d_out, int out_size, void* d_ws, size_t ws_size,
                              hipStream_t stream) {
  const void* x   = d_in[0];
  const int*  ei  = (const int*)d_in[1];
  const int*  bat = (const int*)d_in[2];

  float* f = (float*)d_ws;
  bf16* A = (bf16*)f; f += (size_t)NN * D / 2;   // H1, then H2 (bf16)
  bf16* B = (bf16*)f; f += (size_t)NN * D / 2;   // R1 (bf16)
  float* W1f  = f; f += D * D;
  float* W2f  = f; f += D * D;
  float* Wp1f = f; f += D * DP;
  float* b1f  = f; f += D;
  float* g1f  = f; f += D;
  float* be1f = f; f += D;
  float* b2f  = f; f += D;
  float* g2f  = f; f += D;
  float* be2f = f; f += D;
  float* bp1f = f; f += DP;
  float* Wp2f = f; f += DP;
  float* bp2f = f; f += 4;
  bf16* Wpk1 = (bf16*)f; f += 2048 * 8 / 2;      // 16384 bf16
  bf16* Wpk2 = (bf16*)f; f += 2048 * 8 / 2;
  float* sum1P   = f; f += NSLOT * D;
  float* sumsq1P = f; f += NSLOT * D;
  float* sum2P   = f; f += NSLOT * D;
  float* sumsq2P = f; f += NSLOT * D;
  float* pooled = f; f += (size_t)NG * D;
  float* svec1  = f; f += D;
  float* tW2    = f; f += D;
  float* svec2  = f; f += D;
  float* tvec2  = f; f += D;
  float* isq    = f; f += NN;
  int2* pk     = (int2*)f; f += (size_t)NE * 2;
  int* ro      = (int*)f; f += NN + 1;
  int* cursor  = (int*)f; f += NN;
  int* cnt     = (int*)f; f += NN;
  int* bsum    = (int*)f; f += NB;
  int* bbase   = (int*)f; f += NB;
  int* flag    = (int*)f;

  hipMemsetAsync(cnt, 0, NN * sizeof(int), stream);
  hipMemsetAsync(sum1P, 0, (4 * NSLOT * D + NG * D) * sizeof(float), stream);

  k_detect<<<1, 64, 0, stream>>>((const unsigned short*)x, flag);

  CvtArgs ca;
  ca.s[0] = d_in[3];  ca.d[0] = W1f;  ca.n[0] = D * D;
  ca.s[1] = d_in[7];  ca.d[1] = W2f;  ca.n[1] = D * D;
  ca.s[2] = d_in[11]; ca.d[2] = Wp1f; ca.n[2] = D * DP;
  ca.s[3] = d_in[4];  ca.d[3] = b1f;  ca.n[3] = D;
  ca.s[4] = d_in[5];  ca.d[4] = g1f;  ca.n[4] = D;
  ca.s[5] = d_in[6];  ca.d[5] = be1f; ca.n[5] = D;
  ca.s[6] = d_in[8];  ca.d[6] = b2f;  ca.n[6] = D;
  ca.s[7] = d_in[9];  ca.d[7] = g2f;  ca.n[7] = D;
  ca.s[8] = d_in[10]; ca.d[8] = be2f; ca.n[8] = D;
  ca.s[9] = d_in[12]; ca.d[9] = bp1f; ca.n[9] = DP;
  ca.s[10] = d_in[13]; ca.d[10] = Wp2f; ca.n[10] = DP;
  ca.s[11] = d_in[14]; ca.d[11] = bp2f; ca.n[11] = 1;
  k_cvt<<<12, 256, 0, stream>>>(ca, flag);

  k_deg<<<(NE + 255) / 256, 256, 0, stream>>>(ei, cnt);
  k_bsum<<<NB, 256, 0, stream>>>(cnt, bsum);
  k_bscan<<<1, 256, 0, stream>>>(bsum, bbase);
  k_offsets<<<NB, 256, 0, stream>>>(cnt, bbase, ro, cursor, isq);
  k_fill<<<(NE + 255) / 256, 256, 0, stream>>>(ei, isq, cursor, pk);
  k_pack<<<8, 256, 0, stream>>>(W1f, nullptr, Wpk1);

  // layer 1
  k_mgemm<<<256, 256, 0, stream>>>(x, flag, Wpk1, nullptr, A, NN);
  k_agg<0><<<(NN + 15) / 16, 256, 0, stream>>>(A, ro, pk, b1f, nullptr,
                                               B, sum1P, sumsq1P, nullptr);
  k_bnstats1<<<1, D, 0, stream>>>(sum1P, sumsq1P, g1f, be1f, W2f, svec1, tW2);

  // layer 2 (BN1 scale folded into packed W2; t1@W2 as rowadd)
  k_pack<<<8, 256, 0, stream>>>(W2f, svec1, Wpk2);
  k_mgemm<<<256, 256, 0, stream>>>(B, flag + 1, Wpk2, tW2, A, NN);
  k_agg<1><<<(NN + 15) / 16, 256, 0, stream>>>(A, ro, pk, b2f, bat,
                                               nullptr, sum2P, sumsq2P, pooled);
  k_bnstats2<<<1, D, 0, stream>>>(sum2P, sumsq2P, g2f, be2f, svec2, tvec2);

  k_head<<<NG, DP, 0, stream>>>(pooled, svec2, tvec2, Wp1f, bp1f, Wp2f, bp2f, d_out, flag);
}

// Round 6
// 266.855 us; speedup vs baseline: 5.9102x; 1.4098x over previous
//
#include <hip/hip_runtime.h>

#define NN 50000
#define NE 800000
#define NG 64
#define D 128
#define DP 256
#define BN_EPS 1e-5f
#define NSLOT 32
#define NB 196  // ceil(NN/256)

typedef unsigned short bf16;
typedef __attribute__((ext_vector_type(8))) short s16x8;
typedef __attribute__((ext_vector_type(4))) float f32x4;

__device__ __forceinline__ float bf2f(unsigned h16) {
  unsigned u = (h16 & 0xffffu) << 16; float f; __builtin_memcpy(&f, &u, 4); return f;
}
__device__ __forceinline__ bf16 f2bf(float f) {
  unsigned u; __builtin_memcpy(&u, &f, 4);
  return (bf16)((u + 0x7FFFu + ((u >> 16) & 1u)) >> 16);
}
__device__ __forceinline__ unsigned packbf2(float a, float b) {
  return (unsigned)f2bf(a) | ((unsigned)f2bf(b) << 16);
}
__device__ __forceinline__ s16x8 u4cast(uint4 v) {
  s16x8 r; __builtin_memcpy(&r, &v, 16); return r;
}

// ---------- dtype detection: flag[0]=1 if bf16 input, flag[1]=1 const ----------
__global__ void k_detect(const unsigned short* __restrict__ x, int* __restrict__ flag) {
  if (threadIdx.x == 0) {
    int good = 0;
    for (int i = 0; i < 64; ++i) {
      float v = bf2f(x[2 * i]);
      float a = fabsf(v);
      if (v == 0.0f || (a > 1e-30f && a < 32.0f)) good++;
    }
    flag[0] = (good >= 56) ? 1 : 0;
    flag[1] = 1;
  }
}

// ---------- convert all weight tensors to f32 in ws ----------
struct CvtArgs {
  const void* s[12];
  float* d[12];
  int n[12];
};

__global__ __launch_bounds__(256) void k_cvt(CvtArgs a, const int* __restrict__ flag) {
  int t = blockIdx.x;
  int mode = flag[0];
  const void* sp = a.s[t];
  float* dp = a.d[t];
  int n = a.n[t];
  if (mode) {
    const unsigned short* s = (const unsigned short*)sp;
    for (int i = threadIdx.x; i < n; i += 256) dp[i] = bf2f(s[i]);
  } else {
    const float* s = (const float*)sp;
    for (int i = threadIdx.x; i < n; i += 256) dp[i] = s[i];
  }
}

// ---------- degree count ----------
__global__ __launch_bounds__(256) void k_deg(const int* __restrict__ ei, int* __restrict__ cnt) {
  int e = blockIdx.x * 256 + threadIdx.x;
  if (e < NE) atomicAdd(&cnt[ei[NE + e]], 1);
}

// ---------- scan stage 1: per-block sums ----------
__global__ __launch_bounds__(256) void k_bsum(const int* __restrict__ cnt, int* __restrict__ bsum) {
  int i = blockIdx.x * 256 + threadIdx.x;
  int v = (i < NN) ? cnt[i] : 0;
  __shared__ int s[4];
  for (int off = 32; off; off >>= 1) v += __shfl_down(v, off);
  if ((threadIdx.x & 63) == 0) s[threadIdx.x >> 6] = v;
  __syncthreads();
  if (threadIdx.x == 0) bsum[blockIdx.x] = s[0] + s[1] + s[2] + s[3];
}

// ---------- scan stage 2: exclusive scan of NB partials ----------
__global__ __launch_bounds__(256) void k_bscan(const int* __restrict__ bsum, int* __restrict__ bbase) {
  __shared__ int sh[256];
  int t = threadIdx.x;
  int v = (t < NB) ? bsum[t] : 0;
  sh[t] = v;
  __syncthreads();
  for (int off = 1; off < 256; off <<= 1) {
    int u = (t >= off) ? sh[t - off] : 0;
    __syncthreads();
    sh[t] += u;
    __syncthreads();
  }
  if (t < NB) bbase[t] = sh[t] - v;
}

// ---------- scan stage 3: per-element offsets + cursor + isq ----------
__global__ __launch_bounds__(256) void k_offsets(const int* __restrict__ cnt, const int* __restrict__ bbase,
                                                 int* __restrict__ ro, int* __restrict__ cursor,
                                                 float* __restrict__ isq) {
  __shared__ int sh[256];
  int t = threadIdx.x;
  int i = blockIdx.x * 256 + t;
  int c = (i < NN) ? cnt[i] : 0;
  sh[t] = c;
  __syncthreads();
  for (int off = 1; off < 256; off <<= 1) {
    int u = (t >= off) ? sh[t - off] : 0;
    __syncthreads();
    sh[t] += u;
    __syncthreads();
  }
  if (i < NN) {
    int o = bbase[blockIdx.x] + sh[t] - c;
    ro[i] = o; cursor[i] = o;
    isq[i] = rsqrtf((float)(c + 1));
  }
  if (i == 0) ro[NN] = NE;
}

// ---------- fill CSR: pk[slot] = {src, bits(isq[s]*isq[d])} ----------
__global__ __launch_bounds__(256) void k_fill(const int* __restrict__ ei, const float* __restrict__ isq,
                                              int* __restrict__ cursor, int2* __restrict__ pk) {
  int e = blockIdx.x * 256 + threadIdx.x;
  if (e < NE) {
    int s = ei[e], d = ei[NE + e];
    int slot = atomicAdd(&cursor[d], 1);
    int2 v; v.x = s; v.y = __float_as_int(isq[s] * isq[d]);
    pk[slot] = v;
  }
}

// ---------- pack W (f32 [D][D], optional row-scale by scale[k]) into MFMA B-frag layout ----------
// slot = ((kc*8 + ct)*64 + lane); element j = W[kc*32 + (lane>>4)*8 + j][ct*16 + (lane&15)]
__global__ __launch_bounds__(256) void k_pack(const float* __restrict__ W, const float* __restrict__ scale,
                                              bf16* __restrict__ Wp) {
  int slot = blockIdx.x * 256 + threadIdx.x;
  if (slot >= 2048) return;
  int kc = slot >> 9, ct = (slot >> 6) & 7, l = slot & 63;
  int q = l >> 4, p = l & 15;
  int n = ct * 16 + p;
  unsigned u[4];
#pragma unroll
  for (int jj = 0; jj < 4; ++jj) {
    int k0 = kc * 32 + q * 8 + jj * 2;
    float w0 = W[k0 * D + n], w1 = W[(k0 + 1) * D + n];
    if (scale) { w0 *= scale[k0]; w1 *= scale[k0 + 1]; }
    u[jj] = packbf2(w0, w1);
  }
  uint4 o = make_uint4(u[0], u[1], u[2], u[3]);
  *(uint4*)(Wp + (size_t)slot * 8) = o;
}

// ---------- MFMA GEMM: Out[n][:] = X[n][:] @ Wpacked + (rowadd?:0), bf16 out ----------
// 256 thr = 4 waves; wave owns 16 rows x 128 cols; K=128 in 4 chunks of 32.
__global__ __launch_bounds__(256) void k_mgemm(const void* __restrict__ Xv, const int* __restrict__ flag,
                                               const bf16* __restrict__ Wp,
                                               const float* __restrict__ rowadd,
                                               bf16* __restrict__ Out, int nrows) {
  __shared__ float Cs[4][16][D + 4];   // pad 4 floats: breaks 4-way write conflict, keeps 16B align
  int l = threadIdx.x & 63, w = threadIdx.x >> 6;
  int q = l >> 4, p = l & 15;
  int mode = flag ? flag[0] : 0;
  float rv[8];
#pragma unroll
  for (int ct = 0; ct < 8; ++ct) rv[ct] = rowadd ? rowadd[ct * 16 + p] : 0.f;
  int ntiles = (nrows + 63) >> 6;
  for (int t = blockIdx.x; t < ntiles; t += gridDim.x) {
    int wb = t * 64 + w * 16;
    int rowc = min(wb + p, nrows - 1);
    f32x4 acc[8];
#pragma unroll
    for (int ct = 0; ct < 8; ++ct) { f32x4 z = {rv[ct], rv[ct], rv[ct], rv[ct]}; acc[ct] = z; }
#pragma unroll
    for (int kc = 0; kc < 4; ++kc) {
      s16x8 a;
      if (mode) {
        uint4 av = *(const uint4*)((const bf16*)Xv + (size_t)rowc * D + kc * 32 + q * 8);
        a = u4cast(av);
      } else {
        const float* Xf = (const float*)Xv + (size_t)rowc * D + kc * 32 + q * 8;
        float4 f0 = *(const float4*)Xf;
        float4 f1 = *(const float4*)(Xf + 4);
        uint4 u = make_uint4(packbf2(f0.x, f0.y), packbf2(f0.z, f0.w),
                             packbf2(f1.x, f1.y), packbf2(f1.z, f1.w));
        a = u4cast(u);
      }
#pragma unroll
      for (int ct = 0; ct < 8; ++ct) {
        s16x8 bfr = *(const s16x8*)(Wp + (size_t)(((kc << 3) + ct) * 64 + l) * 8);
        acc[ct] = __builtin_amdgcn_mfma_f32_16x16x32_bf16(a, bfr, acc[ct], 0, 0, 0);
      }
    }
#pragma unroll
    for (int ct = 0; ct < 8; ++ct)
#pragma unroll
      for (int r = 0; r < 4; ++r)
        Cs[w][q * 4 + r][ct * 16 + p] = acc[ct][r];
    __syncthreads();
#pragma unroll
    for (int i = 0; i < 4; ++i) {
      int idx = i * 64 + l;
      int rr = idx >> 4, c8 = idx & 15;
      int gr = t * 64 + w * 16 + rr;
      if (gr < nrows) {
        float4 v0 = *(const float4*)&Cs[w][rr][c8 * 8];
        float4 v1 = *(const float4*)&Cs[w][rr][c8 * 8 + 4];
        uint4 o = make_uint4(packbf2(v0.x, v0.y), packbf2(v0.z, v0.w),
                             packbf2(v1.x, v1.y), packbf2(v1.z, v1.w));
        *(uint4*)(Out + (size_t)gr * D + c8 * 8) = o;
      }
    }
    __syncthreads();
  }
}

// ---------- CSR aggregation + fused epilogue (H bf16) ----------
// Lean per-lane state (2 cols/lane); 4-deep edge unroll for 4 gathers in flight.
template <int LAYER2>
__global__ __launch_bounds__(256) void k_agg(const bf16* __restrict__ H, const int* __restrict__ ro,
                                             const int2* __restrict__ pk,
                                             const float* __restrict__ b, const int* __restrict__ batch,
                                             bf16* __restrict__ Rout,
                                             float* __restrict__ sumP, float* __restrict__ sumsqP,
                                             float* __restrict__ pooled) {
  int lane = threadIdx.x & 63;
  int w = __builtin_amdgcn_readfirstlane(threadIdx.x >> 6);
  int nbase = blockIdx.x * 16 + w * 4;
  float2 bv = ((const float2*)b)[lane];
  float2 ls = make_float2(0.f, 0.f), lq = make_float2(0.f, 0.f);
  int gcur = -1; float2 mx = make_float2(0.f, 0.f);
  int nend = min(nbase + 4, NN);
  for (int n = nbase; n < nend; ++n) {
    int r0 = __builtin_amdgcn_readfirstlane(ro[n]);
    int r1 = __builtin_amdgcn_readfirstlane(ro[n + 1]);
    float invd = 1.0f / (float)(r1 - r0 + 1);
    unsigned hv = ((const unsigned*)(H + (size_t)n * D))[lane];
    float2 acc = make_float2(bf2f(hv & 0xffff) * invd, bf2f(hv >> 16) * invd);
    int e = r0;
    for (; e + 4 <= r1; e += 4) {
      int2 p0 = pk[e], p1 = pk[e + 1], p2 = pk[e + 2], p3 = pk[e + 3];
      unsigned x0 = ((const unsigned*)(H + (size_t)p0.x * D))[lane];
      unsigned x1 = ((const unsigned*)(H + (size_t)p1.x * D))[lane];
      unsigned x2 = ((const unsigned*)(H + (size_t)p2.x * D))[lane];
      unsigned x3 = ((const unsigned*)(H + (size_t)p3.x * D))[lane];
      float c0 = __int_as_float(p0.y), c1 = __int_as_float(p1.y);
      float c2 = __int_as_float(p2.y), c3 = __int_as_float(p3.y);
      acc.x += bf2f(x0 & 0xffff) * c0; acc.y += bf2f(x0 >> 16) * c0;
      acc.x += bf2f(x1 & 0xffff) * c1; acc.y += bf2f(x1 >> 16) * c1;
      acc.x += bf2f(x2 & 0xffff) * c2; acc.y += bf2f(x2 >> 16) * c2;
      acc.x += bf2f(x3 & 0xffff) * c3; acc.y += bf2f(x3 >> 16) * c3;
    }
    for (; e < r1; ++e) {
      int2 p0 = pk[e];
      unsigned x0 = ((const unsigned*)(H + (size_t)p0.x * D))[lane];
      float c0 = __int_as_float(p0.y);
      acc.x += bf2f(x0 & 0xffff) * c0; acc.y += bf2f(x0 >> 16) * c0;
    }
    float2 r = make_float2(fmaxf(acc.x + bv.x, 0.f), fmaxf(acc.y + bv.y, 0.f));
    if (!LAYER2) ((unsigned*)(Rout + (size_t)n * D))[lane] = packbf2(r.x, r.y);
    ls.x += r.x; ls.y += r.y; lq.x += r.x * r.x; lq.y += r.y * r.y;
    if (LAYER2) {
      int g = batch[n];
      if (g != gcur) {
        if (gcur >= 0) {
          atomicMax((int*)&pooled[(size_t)gcur * D + 2 * lane], __float_as_int(mx.x));
          atomicMax((int*)&pooled[(size_t)gcur * D + 2 * lane + 1], __float_as_int(mx.y));
        }
        gcur = g; mx = make_float2(0.f, 0.f);
      }
      mx.x = fmaxf(mx.x, r.x); mx.y = fmaxf(mx.y, r.y);
    }
  }
  if (LAYER2 && gcur >= 0) {
    atomicMax((int*)&pooled[(size_t)gcur * D + 2 * lane], __float_as_int(mx.x));
    atomicMax((int*)&pooled[(size_t)gcur * D + 2 * lane + 1], __float_as_int(mx.y));
  }
  __shared__ float ss[4][D], sq[4][D];
  ss[w][2 * lane] = ls.x; ss[w][2 * lane + 1] = ls.y;
  sq[w][2 * lane] = lq.x; sq[w][2 * lane + 1] = lq.y;
  __syncthreads();
  int slot = (blockIdx.x & (NSLOT - 1)) * D;
  if (threadIdx.x < D) {
    int k = threadIdx.x;
    atomicAdd(&sumP[slot + k], ss[0][k] + ss[1][k] + ss[2][k] + ss[3][k]);
  } else {
    int k = threadIdx.x - D;
    atomicAdd(&sumsqP[slot + k], sq[0][k] + sq[1][k] + sq[2][k] + sq[3][k]);
  }
}

// ---------- BN stats from sliced partials; layer1 also folds t1 @ W2 ----------
__global__ void k_bnstats1(const float* __restrict__ sumP, const float* __restrict__ sumsqP,
                           const float* __restrict__ gamma, const float* __restrict__ beta,
                           const float* __restrict__ W2,
                           float* __restrict__ svec, float* __restrict__ tW2) {
  __shared__ float t[D];
  int k = threadIdx.x;
  float sm = 0.f, sq = 0.f;
  for (int i = 0; i < NSLOT; ++i) { sm += sumP[i * D + k]; sq += sumsqP[i * D + k]; }
  float mean = sm * (1.0f / NN);
  float var = sq * (1.0f / NN) - mean * mean;
  float s = gamma[k] * rsqrtf(var + BN_EPS);
  svec[k] = s;
  t[k] = beta[k] - mean * s;
  __syncthreads();
  float acc = 0.f;
  for (int kk = 0; kk < D; ++kk) acc += t[kk] * W2[kk * D + k];
  tW2[k] = acc;
}

__global__ void k_bnstats2(const float* __restrict__ sumP, const float* __restrict__ sumsqP,
                           const float* __restrict__ gamma, const float* __restrict__ beta,
                           float* __restrict__ svec, float* __restrict__ tvec) {
  int k = threadIdx.x;
  float sm = 0.f, sq = 0.f;
  for (int i = 0; i < NSLOT; ++i) { sm += sumP[i * D + k]; sq += sumsqP[i * D + k]; }
  float mean = sm * (1.0f / NN);
  float var = sq * (1.0f / NN) - mean * mean;
  float s = gamma[k] * rsqrtf(var + BN_EPS);
  svec[k] = s;
  tvec[k] = beta[k] - mean * s;
}

// ---------- head MLP ----------
__global__ __launch_bounds__(256) void k_head(const float* __restrict__ pooled, const float* __restrict__ s2,
                                              const float* __restrict__ t2, const float* __restrict__ Wp1,
                                              const float* __restrict__ bp1, const float* __restrict__ Wp2,
                                              const float* __restrict__ bp2, void* out,
                                              const int* __restrict__ flag) {
  __shared__ float y[D];
  __shared__ float wr[4];
  int g = blockIdx.x, j = threadIdx.x;
  if (j < D) y[j] = pooled[(size_t)g * D + j] * s2[j] + t2[j];
  __syncthreads();
  float acc = bp1[j];
#pragma unroll 4
  for (int k = 0; k < D; ++k) acc += y[k] * Wp1[k * DP + j];
  float v = fmaxf(acc, 0.f) * Wp2[j];
  for (int off = 32; off; off >>= 1) v += __shfl_down(v, off);
  if ((j & 63) == 0) wr[j >> 6] = v;
  __syncthreads();
  if (j == 0) {
    float r = wr[0] + wr[1] + wr[2] + wr[3] + bp2[0];
    if (flag[0]) ((bf16*)out)[g] = f2bf(r);
    else ((float*)out)[g] = r;
  }
}

extern "C" void kernel_launch(void* const* d_in, const int* in_sizes, int n_in,
                              void* d_out, int out_size, void* d_ws, size_t ws_size,
                              hipStream_t stream) {
  const void* x   = d_in[0];
  const int*  ei  = (const int*)d_in[1];
  const int*  bat = (const int*)d_in[2];

  float* f = (float*)d_ws;
  bf16* A = (bf16*)f; f += (size_t)NN * D / 2;   // H1, then H2 (bf16)
  bf16* B = (bf16*)f; f += (size_t)NN * D / 2;   // R1 (bf16)
  float* W1f  = f; f += D * D;
  float* W2f  = f; f += D * D;
  float* Wp1f = f; f += D * DP;
  float* b1f  = f; f += D;
  float* g1f  = f; f += D;
  float* be1f = f; f += D;
  float* b2f  = f; f += D;
  float* g2f  = f; f += D;
  float* be2f = f; f += D;
  float* bp1f = f; f += DP;
  float* Wp2f = f; f += DP;
  float* bp2f = f; f += 4;
  bf16* Wpk1 = (bf16*)f; f += 2048 * 8 / 2;      // 16384 bf16
  bf16* Wpk2 = (bf16*)f; f += 2048 * 8 / 2;
  float* sum1P   = f; f += NSLOT * D;
  float* sumsq1P = f; f += NSLOT * D;
  float* sum2P   = f; f += NSLOT * D;
  float* sumsq2P = f; f += NSLOT * D;
  float* pooled = f; f += (size_t)NG * D;
  float* svec1  = f; f += D;
  float* tW2    = f; f += D;
  float* svec2  = f; f += D;
  float* tvec2  = f; f += D;
  float* isq    = f; f += NN;
  int2* pk     = (int2*)f; f += (size_t)NE * 2;
  int* ro      = (int*)f; f += NN + 1;
  int* cursor  = (int*)f; f += NN;
  int* cnt     = (int*)f; f += NN;
  int* bsum    = (int*)f; f += NB;
  int* bbase   = (int*)f; f += NB;
  int* flag    = (int*)f;

  hipMemsetAsync(cnt, 0, NN * sizeof(int), stream);
  hipMemsetAsync(sum1P, 0, (4 * NSLOT * D + NG * D) * sizeof(float), stream);

  k_detect<<<1, 64, 0, stream>>>((const unsigned short*)x, flag);

  CvtArgs ca;
  ca.s[0] = d_in[3];  ca.d[0] = W1f;  ca.n[0] = D * D;
  ca.s[1] = d_in[7];  ca.d[1] = W2f;  ca.n[1] = D * D;
  ca.s[2] = d_in[11]; ca.d[2] = Wp1f; ca.n[2] = D * DP;
  ca.s[3] = d_in[4];  ca.d[3] = b1f;  ca.n[3] = D;
  ca.s[4] = d_in[5];  ca.d[4] = g1f;  ca.n[4] = D;
  ca.s[5] = d_in[6];  ca.d[5] = be1f; ca.n[5] = D;
  ca.s[6] = d_in[8];  ca.d[6] = b2f;  ca.n[6] = D;
  ca.s[7] = d_in[9];  ca.d[7] = g2f;  ca.n[7] = D;
  ca.s[8] = d_in[10]; ca.d[8] = be2f; ca.n[8] = D;
  ca.s[9] = d_in[12]; ca.d[9] = bp1f; ca.n[9] = DP;
  ca.s[10] = d_in[13]; ca.d[10] = Wp2f; ca.n[10] = DP;
  ca.s[11] = d_in[14]; ca.d[11] = bp2f; ca.n[11] = 1;
  k_cvt<<<12, 256, 0, stream>>>(ca, flag);

  k_deg<<<(NE + 255) / 256, 256, 0, stream>>>(ei, cnt);
  k_bsum<<<NB, 256, 0, stream>>>(cnt, bsum);
  k_bscan<<<1, 256, 0, stream>>>(bsum, bbase);
  k_offsets<<<NB, 256, 0, stream>>>(cnt, bbase, ro, cursor, isq);
  k_fill<<<(NE + 255) / 256, 256, 0, stream>>>(ei, isq, cursor, pk);
  k_pack<<<8, 256, 0, stream>>>(W1f, nullptr, Wpk1);

  // layer 1
  k_mgemm<<<256, 256, 0, stream>>>(x, flag, Wpk1, nullptr, A, NN);
  k_agg<0><<<(NN + 15) / 16, 256, 0, stream>>>(A, ro, pk, b1f, nullptr,
                                               B, sum1P, sumsq1P, nullptr);
  k_bnstats1<<<1, D, 0, stream>>>(sum1P, sumsq1P, g1f, be1f, W2f, svec1, tW2);

  // layer 2 (BN1 scale folded into packed W2; t1@W2 as rowadd)
  k_pack<<<8, 256, 0, stream>>>(W2f, svec1, Wpk2);
  k_mgemm<<<256, 256, 0, stream>>>(B, flag + 1, Wpk2, tW2, A, NN);
  k_agg<1><<<(NN + 15) / 16, 256, 0, stream>>>(A, ro, pk, b2f, bat,
                                               nullptr, sum2P, sumsq2P, pooled);
  k_bnstats2<<<1, D, 0, stream>>>(sum2P, sumsq2P, g2f, be2f, svec2, tvec2);

  k_head<<<NG, DP, 0, stream>>>(pooled, svec2, tvec2, Wp1f, bp1f, Wp2f, bp2f, d_out, flag);
}

// Round 7
// 231.303 us; speedup vs baseline: 6.8186x; 1.1537x over previous
//
#include <hip/hip_runtime.h>

#define NN 50000
#define NE 800000
#define NG 64
#define D 128
#define DP 256
#define BN_EPS 1e-5f
#define NSLOT 32
#define NB 196  // ceil(NN/256)

typedef unsigned short bf16;
typedef __attribute__((ext_vector_type(8))) short s16x8;
typedef __attribute__((ext_vector_type(4))) float f32x4;

__device__ __forceinline__ float bf2f(unsigned h16) {
  unsigned u = (h16 & 0xffffu) << 16; float f; __builtin_memcpy(&f, &u, 4); return f;
}
__device__ __forceinline__ bf16 f2bf(float f) {
  unsigned u; __builtin_memcpy(&u, &f, 4);
  return (bf16)((u + 0x7FFFu + ((u >> 16) & 1u)) >> 16);
}
__device__ __forceinline__ unsigned packbf2(float a, float b) {
  return (unsigned)f2bf(a) | ((unsigned)f2bf(b) << 16);
}
__device__ __forceinline__ s16x8 u4cast(uint4 v) {
  s16x8 r; __builtin_memcpy(&r, &v, 16); return r;
}

// ---------- dtype detection (wave-parallel): flag[0]=1 if bf16 input ----------
__global__ void k_detect(const unsigned short* __restrict__ x, int* __restrict__ flag) {
  int i = threadIdx.x;  // 64 lanes
  float v = bf2f(x[2 * i]);
  float a = fabsf(v);
  int good = (v == 0.0f) || (a > 1e-30f && a < 32.0f);
  unsigned long long m = __ballot(good);
  if (i == 0) {
    flag[0] = (__popcll(m) >= 56) ? 1 : 0;
    flag[1] = 1;
  }
}

// ---------- convert weight tensors to f32 (vectorized, chunked) ----------
struct CvtArgs {
  const void* s[12];
  float* d[12];
  int n[12];
};

__global__ __launch_bounds__(256) void k_cvt(CvtArgs a, const int* __restrict__ flag) {
  int t = blockIdx.y;
  int n = a.n[t];
  int base = blockIdx.x * 2048;
  if (base >= n) return;
  int mode = flag[0];
  float* dp = a.d[t];
  if (n >= 8) {
    int i8 = base + threadIdx.x * 8;
    if (i8 + 8 <= n) {
      if (mode) {
        uint4 raw = *(const uint4*)((const bf16*)a.s[t] + i8);
        float4 o0 = make_float4(bf2f(raw.x & 0xffff), bf2f(raw.x >> 16),
                                bf2f(raw.y & 0xffff), bf2f(raw.y >> 16));
        float4 o1 = make_float4(bf2f(raw.z & 0xffff), bf2f(raw.z >> 16),
                                bf2f(raw.w & 0xffff), bf2f(raw.w >> 16));
        *(float4*)(dp + i8) = o0;
        *(float4*)(dp + i8 + 4) = o1;
      } else {
        const float* s = (const float*)a.s[t] + i8;
        *(float4*)(dp + i8) = *(const float4*)s;
        *(float4*)(dp + i8 + 4) = *(const float4*)(s + 4);
      }
    }
  } else {
    int i = base + threadIdx.x;
    if (i < n) dp[i] = mode ? bf2f(((const bf16*)a.s[t])[i]) : ((const float*)a.s[t])[i];
  }
}

// ---------- degree count ----------
__global__ __launch_bounds__(256) void k_deg(const int* __restrict__ ei, int* __restrict__ cnt) {
  int e = blockIdx.x * 256 + threadIdx.x;
  if (e < NE) atomicAdd(&cnt[ei[NE + e]], 1);
}

// ---------- scan stage 1: per-block sums ----------
__global__ __launch_bounds__(256) void k_bsum(const int* __restrict__ cnt, int* __restrict__ bsum) {
  int i = blockIdx.x * 256 + threadIdx.x;
  int v = (i < NN) ? cnt[i] : 0;
  __shared__ int s[4];
  for (int off = 32; off; off >>= 1) v += __shfl_down(v, off);
  if ((threadIdx.x & 63) == 0) s[threadIdx.x >> 6] = v;
  __syncthreads();
  if (threadIdx.x == 0) bsum[blockIdx.x] = s[0] + s[1] + s[2] + s[3];
}

// ---------- scan stage 2: exclusive scan of NB partials ----------
__global__ __launch_bounds__(256) void k_bscan(const int* __restrict__ bsum, int* __restrict__ bbase) {
  __shared__ int sh[256];
  int t = threadIdx.x;
  int v = (t < NB) ? bsum[t] : 0;
  sh[t] = v;
  __syncthreads();
  for (int off = 1; off < 256; off <<= 1) {
    int u = (t >= off) ? sh[t - off] : 0;
    __syncthreads();
    sh[t] += u;
    __syncthreads();
  }
  if (t < NB) bbase[t] = sh[t] - v;
}

// ---------- scan stage 3: per-element offsets + cursor + isq ----------
__global__ __launch_bounds__(256) void k_offsets(const int* __restrict__ cnt, const int* __restrict__ bbase,
                                                 int* __restrict__ ro, int* __restrict__ cursor,
                                                 float* __restrict__ isq) {
  __shared__ int sh[256];
  int t = threadIdx.x;
  int i = blockIdx.x * 256 + t;
  int c = (i < NN) ? cnt[i] : 0;
  sh[t] = c;
  __syncthreads();
  for (int off = 1; off < 256; off <<= 1) {
    int u = (t >= off) ? sh[t - off] : 0;
    __syncthreads();
    sh[t] += u;
    __syncthreads();
  }
  if (i < NN) {
    int o = bbase[blockIdx.x] + sh[t] - c;
    ro[i] = o; cursor[i] = o;
    isq[i] = rsqrtf((float)(c + 1));
  }
  if (i == 0) ro[NN] = NE;
}

// ---------- fill CSR: pk[slot] = {src, bits(isq[s]*isq[d])} ----------
__global__ __launch_bounds__(256) void k_fill(const int* __restrict__ ei, const float* __restrict__ isq,
                                              int* __restrict__ cursor, int2* __restrict__ pk) {
  int e = blockIdx.x * 256 + threadIdx.x;
  if (e < NE) {
    int s = ei[e], d = ei[NE + e];
    int slot = atomicAdd(&cursor[d], 1);
    int2 v; v.x = s; v.y = __float_as_int(isq[s] * isq[d]);
    pk[slot] = v;
  }
}

// ---------- pack W (f32 [D][D], optional row-scale by scale[k]) into MFMA B-frag layout ----------
__global__ __launch_bounds__(256) void k_pack(const float* __restrict__ W, const float* __restrict__ scale,
                                              bf16* __restrict__ Wp) {
  int slot = blockIdx.x * 256 + threadIdx.x;
  if (slot >= 2048) return;
  int kc = slot >> 9, ct = (slot >> 6) & 7, l = slot & 63;
  int q = l >> 4, p = l & 15;
  int n = ct * 16 + p;
  unsigned u[4];
#pragma unroll
  for (int jj = 0; jj < 4; ++jj) {
    int k0 = kc * 32 + q * 8 + jj * 2;
    float w0 = W[k0 * D + n], w1 = W[(k0 + 1) * D + n];
    if (scale) { w0 *= scale[k0]; w1 *= scale[k0 + 1]; }
    u[jj] = packbf2(w0, w1);
  }
  uint4 o = make_uint4(u[0], u[1], u[2], u[3]);
  *(uint4*)(Wp + (size_t)slot * 8) = o;
}

// ---------- MFMA GEMM: Out[n][:] = X[n][:] @ Wpacked + (rowadd?:0), bf16 out ----------
__global__ __launch_bounds__(256) void k_mgemm(const void* __restrict__ Xv, const int* __restrict__ flag,
                                               const bf16* __restrict__ Wp,
                                               const float* __restrict__ rowadd,
                                               bf16* __restrict__ Out, int nrows) {
  __shared__ float Cs[4][16][D + 4];
  int l = threadIdx.x & 63, w = threadIdx.x >> 6;
  int q = l >> 4, p = l & 15;
  int mode = flag ? flag[0] : 0;
  float rv[8];
#pragma unroll
  for (int ct = 0; ct < 8; ++ct) rv[ct] = rowadd ? rowadd[ct * 16 + p] : 0.f;
  int ntiles = (nrows + 63) >> 6;
  for (int t = blockIdx.x; t < ntiles; t += gridDim.x) {
    int wb = t * 64 + w * 16;
    int rowc = min(wb + p, nrows - 1);
    f32x4 acc[8];
#pragma unroll
    for (int ct = 0; ct < 8; ++ct) { f32x4 z = {rv[ct], rv[ct], rv[ct], rv[ct]}; acc[ct] = z; }
#pragma unroll
    for (int kc = 0; kc < 4; ++kc) {
      s16x8 a;
      if (mode) {
        uint4 av = *(const uint4*)((const bf16*)Xv + (size_t)rowc * D + kc * 32 + q * 8);
        a = u4cast(av);
      } else {
        const float* Xf = (const float*)Xv + (size_t)rowc * D + kc * 32 + q * 8;
        float4 f0 = *(const float4*)Xf;
        float4 f1 = *(const float4*)(Xf + 4);
        uint4 u = make_uint4(packbf2(f0.x, f0.y), packbf2(f0.z, f0.w),
                             packbf2(f1.x, f1.y), packbf2(f1.z, f1.w));
        a = u4cast(u);
      }
#pragma unroll
      for (int ct = 0; ct < 8; ++ct) {
        s16x8 bfr = *(const s16x8*)(Wp + (size_t)(((kc << 3) + ct) * 64 + l) * 8);
        acc[ct] = __builtin_amdgcn_mfma_f32_16x16x32_bf16(a, bfr, acc[ct], 0, 0, 0);
      }
    }
#pragma unroll
    for (int ct = 0; ct < 8; ++ct)
#pragma unroll
      for (int r = 0; r < 4; ++r)
        Cs[w][q * 4 + r][ct * 16 + p] = acc[ct][r];
    __syncthreads();
#pragma unroll
    for (int i = 0; i < 4; ++i) {
      int idx = i * 64 + l;
      int rr = idx >> 4, c8 = idx & 15;
      int gr = t * 64 + w * 16 + rr;
      if (gr < nrows) {
        float4 v0 = *(const float4*)&Cs[w][rr][c8 * 8];
        float4 v1 = *(const float4*)&Cs[w][rr][c8 * 8 + 4];
        uint4 o = make_uint4(packbf2(v0.x, v0.y), packbf2(v0.z, v0.w),
                             packbf2(v1.x, v1.y), packbf2(v1.z, v1.w));
        *(uint4*)(Out + (size_t)gr * D + c8 * 8) = o;
      }
    }
    __syncthreads();
  }
}

// ---------- CSR aggregation + fused epilogue (H bf16) ----------
// Lean per-lane state (2 cols/lane); 8-deep edge unroll -> 8 gathers in flight.
template <int LAYER2>
__global__ __launch_bounds__(256) void k_agg(const bf16* __restrict__ H, const int* __restrict__ ro,
                                             const int2* __restrict__ pk,
                                             const float* __restrict__ b, const int* __restrict__ batch,
                                             bf16* __restrict__ Rout,
                                             float* __restrict__ sumP, float* __restrict__ sumsqP,
                                             float* __restrict__ pooled) {
  int lane = threadIdx.x & 63;
  int w = __builtin_amdgcn_readfirstlane(threadIdx.x >> 6);
  int nbase = blockIdx.x * 16 + w * 4;
  float2 bv = ((const float2*)b)[lane];
  float2 ls = make_float2(0.f, 0.f), lq = make_float2(0.f, 0.f);
  int gcur = -1; float2 mx = make_float2(0.f, 0.f);
  int nend = min(nbase + 4, NN);
  for (int n = nbase; n < nend; ++n) {
    int r0 = __builtin_amdgcn_readfirstlane(ro[n]);
    int r1 = __builtin_amdgcn_readfirstlane(ro[n + 1]);
    float invd = 1.0f / (float)(r1 - r0 + 1);
    unsigned hv = ((const unsigned*)(H + (size_t)n * D))[lane];
    float2 acc = make_float2(bf2f(hv & 0xffff) * invd, bf2f(hv >> 16) * invd);
    int e = r0;
    for (; e + 8 <= r1; e += 8) {
      int2 P[8];
      unsigned X[8];
#pragma unroll
      for (int j = 0; j < 8; ++j) P[j] = pk[e + j];
#pragma unroll
      for (int j = 0; j < 8; ++j) X[j] = ((const unsigned*)(H + (size_t)P[j].x * D))[lane];
#pragma unroll
      for (int j = 0; j < 8; ++j) {
        float c = __int_as_float(P[j].y);
        acc.x += bf2f(X[j] & 0xffff) * c; acc.y += bf2f(X[j] >> 16) * c;
      }
    }
    for (; e + 4 <= r1; e += 4) {
      int2 p0 = pk[e], p1 = pk[e + 1], p2 = pk[e + 2], p3 = pk[e + 3];
      unsigned x0 = ((const unsigned*)(H + (size_t)p0.x * D))[lane];
      unsigned x1 = ((const unsigned*)(H + (size_t)p1.x * D))[lane];
      unsigned x2 = ((const unsigned*)(H + (size_t)p2.x * D))[lane];
      unsigned x3 = ((const unsigned*)(H + (size_t)p3.x * D))[lane];
      float c0 = __int_as_float(p0.y), c1 = __int_as_float(p1.y);
      float c2 = __int_as_float(p2.y), c3 = __int_as_float(p3.y);
      acc.x += bf2f(x0 & 0xffff) * c0; acc.y += bf2f(x0 >> 16) * c0;
      acc.x += bf2f(x1 & 0xffff) * c1; acc.y += bf2f(x1 >> 16) * c1;
      acc.x += bf2f(x2 & 0xffff) * c2; acc.y += bf2f(x2 >> 16) * c2;
      acc.x += bf2f(x3 & 0xffff) * c3; acc.y += bf2f(x3 >> 16) * c3;
    }
    for (; e < r1; ++e) {
      int2 p0 = pk[e];
      unsigned x0 = ((const unsigned*)(H + (size_t)p0.x * D))[lane];
      float c0 = __int_as_float(p0.y);
      acc.x += bf2f(x0 & 0xffff) * c0; acc.y += bf2f(x0 >> 16) * c0;
    }
    float2 r = make_float2(fmaxf(acc.x + bv.x, 0.f), fmaxf(acc.y + bv.y, 0.f));
    if (!LAYER2) ((unsigned*)(Rout + (size_t)n * D))[lane] = packbf2(r.x, r.y);
    ls.x += r.x; ls.y += r.y; lq.x += r.x * r.x; lq.y += r.y * r.y;
    if (LAYER2) {
      int g = batch[n];
      if (g != gcur) {
        if (gcur >= 0) {
          atomicMax((int*)&pooled[(size_t)gcur * D + 2 * lane], __float_as_int(mx.x));
          atomicMax((int*)&pooled[(size_t)gcur * D + 2 * lane + 1], __float_as_int(mx.y));
        }
        gcur = g; mx = make_float2(0.f, 0.f);
      }
      mx.x = fmaxf(mx.x, r.x); mx.y = fmaxf(mx.y, r.y);
    }
  }
  if (LAYER2 && gcur >= 0) {
    atomicMax((int*)&pooled[(size_t)gcur * D + 2 * lane], __float_as_int(mx.x));
    atomicMax((int*)&pooled[(size_t)gcur * D + 2 * lane + 1], __float_as_int(mx.y));
  }
  __shared__ float ss[4][D], sq[4][D];
  ss[w][2 * lane] = ls.x; ss[w][2 * lane + 1] = ls.y;
  sq[w][2 * lane] = lq.x; sq[w][2 * lane + 1] = lq.y;
  __syncthreads();
  int slot = (blockIdx.x & (NSLOT - 1)) * D;
  if (threadIdx.x < D) {
    int k = threadIdx.x;
    atomicAdd(&sumP[slot + k], ss[0][k] + ss[1][k] + ss[2][k] + ss[3][k]);
  } else {
    int k = threadIdx.x - D;
    atomicAdd(&sumsqP[slot + k], sq[0][k] + sq[1][k] + sq[2][k] + sq[3][k]);
  }
}

// ---------- BN stats from sliced partials; layer1 also folds t1 @ W2 ----------
__global__ void k_bnstats1(const float* __restrict__ sumP, const float* __restrict__ sumsqP,
                           const float* __restrict__ gamma, const float* __restrict__ beta,
                           const float* __restrict__ W2,
                           float* __restrict__ svec, float* __restrict__ tW2) {
  __shared__ float t[D];
  int k = threadIdx.x;
  float sm = 0.f, sq = 0.f;
  for (int i = 0; i < NSLOT; ++i) { sm += sumP[i * D + k]; sq += sumsqP[i * D + k]; }
  float mean = sm * (1.0f / NN);
  float var = sq * (1.0f / NN) - mean * mean;
  float s = gamma[k] * rsqrtf(var + BN_EPS);
  svec[k] = s;
  t[k] = beta[k] - mean * s;
  __syncthreads();
  float acc = 0.f;
  for (int kk = 0; kk < D; ++kk) acc += t[kk] * W2[kk * D + k];
  tW2[k] = acc;
}

__global__ void k_bnstats2(const float* __restrict__ sumP, const float* __restrict__ sumsqP,
                           const float* __restrict__ gamma, const float* __restrict__ beta,
                           float* __restrict__ svec, float* __restrict__ tvec) {
  int k = threadIdx.x;
  float sm = 0.f, sq = 0.f;
  for (int i = 0; i < NSLOT; ++i) { sm += sumP[i * D + k]; sq += sumsqP[i * D + k]; }
  float mean = sm * (1.0f / NN);
  float var = sq * (1.0f / NN) - mean * mean;
  float s = gamma[k] * rsqrtf(var + BN_EPS);
  svec[k] = s;
  tvec[k] = beta[k] - mean * s;
}

// ---------- head MLP ----------
__global__ __launch_bounds__(256) void k_head(const float* __restrict__ pooled, const float* __restrict__ s2,
                                              const float* __restrict__ t2, const float* __restrict__ Wp1,
                                              const float* __restrict__ bp1, const float* __restrict__ Wp2,
                                              const float* __restrict__ bp2, void* out,
                                              const int* __restrict__ flag) {
  __shared__ float y[D];
  __shared__ float wr[4];
  int g = blockIdx.x, j = threadIdx.x;
  if (j < D) y[j] = pooled[(size_t)g * D + j] * s2[j] + t2[j];
  __syncthreads();
  float acc = bp1[j];
#pragma unroll 4
  for (int k = 0; k < D; ++k) acc += y[k] * Wp1[k * DP + j];
  float v = fmaxf(acc, 0.f) * Wp2[j];
  for (int off = 32; off; off >>= 1) v += __shfl_down(v, off);
  if ((j & 63) == 0) wr[j >> 6] = v;
  __syncthreads();
  if (j == 0) {
    float r = wr[0] + wr[1] + wr[2] + wr[3] + bp2[0];
    if (flag[0]) ((bf16*)out)[g] = f2bf(r);
    else ((float*)out)[g] = r;
  }
}

extern "C" void kernel_launch(void* const* d_in, const int* in_sizes, int n_in,
                              void* d_out, int out_size, void* d_ws, size_t ws_size,
                              hipStream_t stream) {
  const void* x   = d_in[0];
  const int*  ei  = (const int*)d_in[1];
  const int*  bat = (const int*)d_in[2];

  float* f = (float*)d_ws;
  bf16* A = (bf16*)f; f += (size_t)NN * D / 2;   // H1, then H2 (bf16)
  bf16* B = (bf16*)f; f += (size_t)NN * D / 2;   // R1 (bf16)
  float* W1f  = f; f += D * D;
  float* W2f  = f; f += D * D;
  float* Wp1f = f; f += D * DP;
  float* b1f  = f; f += D;
  float* g1f  = f; f += D;
  float* be1f = f; f += D;
  float* b2f  = f; f += D;
  float* g2f  = f; f += D;
  float* be2f = f; f += D;
  float* bp1f = f; f += DP;
  float* Wp2f = f; f += DP;
  float* bp2f = f; f += 4;
  bf16* Wpk1 = (bf16*)f; f += 2048 * 8 / 2;      // 16384 bf16
  bf16* Wpk2 = (bf16*)f; f += 2048 * 8 / 2;
  float* sum1P   = f; f += NSLOT * D;
  float* sumsq1P = f; f += NSLOT * D;
  float* sum2P   = f; f += NSLOT * D;
  float* sumsq2P = f; f += NSLOT * D;
  float* pooled = f; f += (size_t)NG * D;
  float* svec1  = f; f += D;
  float* tW2    = f; f += D;
  float* svec2  = f; f += D;
  float* tvec2  = f; f += D;
  float* isq    = f; f += NN;
  int2* pk     = (int2*)f; f += (size_t)NE * 2;
  int* ro      = (int*)f; f += NN + 1;
  int* cursor  = (int*)f; f += NN;
  int* cnt     = (int*)f; f += NN;
  int* bsum    = (int*)f; f += NB;
  int* bbase   = (int*)f; f += NB;
  int* flag    = (int*)f;

  hipMemsetAsync(cnt, 0, NN * sizeof(int), stream);
  hipMemsetAsync(sum1P, 0, (4 * NSLOT * D + NG * D) * sizeof(float), stream);

  k_detect<<<1, 64, 0, stream>>>((const unsigned short*)x, flag);

  CvtArgs ca;
  ca.s[0] = d_in[3];  ca.d[0] = W1f;  ca.n[0] = D * D;
  ca.s[1] = d_in[7];  ca.d[1] = W2f;  ca.n[1] = D * D;
  ca.s[2] = d_in[11]; ca.d[2] = Wp1f; ca.n[2] = D * DP;
  ca.s[3] = d_in[4];  ca.d[3] = b1f;  ca.n[3] = D;
  ca.s[4] = d_in[5];  ca.d[4] = g1f;  ca.n[4] = D;
  ca.s[5] = d_in[6];  ca.d[5] = be1f; ca.n[5] = D;
  ca.s[6] = d_in[8];  ca.d[6] = b2f;  ca.n[6] = D;
  ca.s[7] = d_in[9];  ca.d[7] = g2f;  ca.n[7] = D;
  ca.s[8] = d_in[10]; ca.d[8] = be2f; ca.n[8] = D;
  ca.s[9] = d_in[12]; ca.d[9] = bp1f; ca.n[9] = DP;
  ca.s[10] = d_in[13]; ca.d[10] = Wp2f; ca.n[10] = DP;
  ca.s[11] = d_in[14]; ca.d[11] = bp2f; ca.n[11] = 1;
  k_cvt<<<dim3(16, 12), 256, 0, stream>>>(ca, flag);

  k_deg<<<(NE + 255) / 256, 256, 0, stream>>>(ei, cnt);
  k_bsum<<<NB, 256, 0, stream>>>(cnt, bsum);
  k_bscan<<<1, 256, 0, stream>>>(bsum, bbase);
  k_offsets<<<NB, 256, 0, stream>>>(cnt, bbase, ro, cursor, isq);
  k_fill<<<(NE + 255) / 256, 256, 0, stream>>>(ei, isq, cursor, pk);
  k_pack<<<8, 256, 0, stream>>>(W1f, nullptr, Wpk1);

  // layer 1
  k_mgemm<<<(NN + 63) / 64, 256, 0, stream>>>(x, flag, Wpk1, nullptr, A, NN);
  k_agg<0><<<(NN + 15) / 16, 256, 0, stream>>>(A, ro, pk, b1f, nullptr,
                                               B, sum1P, sumsq1P, nullptr);
  k_bnstats1<<<1, D, 0, stream>>>(sum1P, sumsq1P, g1f, be1f, W2f, svec1, tW2);

  // layer 2 (BN1 scale folded into packed W2; t1@W2 as rowadd)
  k_pack<<<8, 256, 0, stream>>>(W2f, svec1, Wpk2);
  k_mgemm<<<(NN + 63) / 64, 256, 0, stream>>>(B, flag + 1, Wpk2, tW2, A, NN);
  k_agg<1><<<(NN + 15) / 16, 256, 0, stream>>>(A, ro, pk, b2f, bat,
                                               nullptr, sum2P, sumsq2P, pooled);
  k_bnstats2<<<1, D, 0, stream>>>(sum2P, sumsq2P, g2f, be2f, svec2, tvec2);

  k_head<<<NG, DP, 0, stream>>>(pooled, svec2, tvec2, Wp1f, bp1f, Wp2f, bp2f, d_out, flag);
}